// Round 7
// baseline (982.108 us; speedup 1.0000x reference)
//
#include <hip/hip_runtime.h>
#include <hip/hip_bf16.h>

#define IN_CH 64
#define HID 32
#define HEADS 4
#define OUT_CH 6
#define NEG_SLOPE 0.2f

// ---------------- preprocessing: build dst-CSR ----------------

__global__ void hist_kernel(const int* __restrict__ ei, int E, int N, int* __restrict__ cnt) {
    int t = blockIdx.x * blockDim.x + threadIdx.x;
    int e0 = t * 4;
    int EN = E + N;
    if (e0 >= EN) return;
    int d[4];
    if (((E & 3) == 0) && (e0 + 3 < E)) {
        int4 dv = *reinterpret_cast<const int4*>(ei + E + e0);
        d[0] = dv.x; d[1] = dv.y; d[2] = dv.z; d[3] = dv.w;
    } else {
#pragma unroll
        for (int k = 0; k < 4; ++k) {
            int e = e0 + k;
            d[k] = (e < E) ? ei[E + e] : (e < EN ? e - E : -1);
        }
    }
#pragma unroll
    for (int k = 0; k < 4; ++k)
        if (d[k] >= 0) atomicAdd(&cnt[d[k]], 1);
}

#define SCAN_ELEMS 1024

__global__ __launch_bounds__(256) void scan_partial(const int* __restrict__ cnt, int N,
                                                    int* __restrict__ blocksum) {
    __shared__ int red[256];
    int t = threadIdx.x;
    int b0 = blockIdx.x * SCAN_ELEMS;
    int sum = 0;
#pragma unroll
    for (int i = 0; i < SCAN_ELEMS / 256; ++i) {
        int g = b0 + t + i * 256;
        sum += (g < N) ? cnt[g] : 0;
    }
    red[t] = sum;
    __syncthreads();
    for (int off = 128; off; off >>= 1) {
        if (t < off) red[t] += red[t + off];
        __syncthreads();
    }
    if (t == 0) blocksum[blockIdx.x] = red[0];
}

__global__ __launch_bounds__(256) void scan_sums(int* __restrict__ blocksum, int nb) {
    __shared__ int tmp[256];
    int t = threadIdx.x;
    int chunk = (nb + 255) >> 8;
    int s0 = t * chunk, s1 = min(s0 + chunk, nb);
    int sum = 0;
    for (int i = s0; i < s1; ++i) sum += blocksum[i];
    tmp[t] = sum;
    __syncthreads();
    for (int off = 1; off < 256; off <<= 1) {
        int v = (t >= off) ? tmp[t - off] : 0;
        __syncthreads();
        tmp[t] += v;
        __syncthreads();
    }
    int run = (t == 0) ? 0 : tmp[t - 1];
    for (int i = s0; i < s1; ++i) {
        int c = blocksum[i];
        blocksum[i] = run;
        run += c;
    }
}

__global__ __launch_bounds__(256) void scan_apply(const int* __restrict__ cnt, int N, int total,
                                                  const int* __restrict__ blocksum,
                                                  int* __restrict__ row_start,
                                                  int* __restrict__ cursor) {
    __shared__ int tmp[256];
    int t = threadIdx.x;
    int g = blockIdx.x * SCAN_ELEMS + t * 4;
    int4 c = make_int4(0, 0, 0, 0);
    if (g + 3 < N) {
        c = *reinterpret_cast<const int4*>(cnt + g);
    } else {
        if (g + 0 < N) c.x = cnt[g + 0];
        if (g + 1 < N) c.y = cnt[g + 1];
        if (g + 2 < N) c.z = cnt[g + 2];
        if (g + 3 < N) c.w = cnt[g + 3];
    }
    tmp[t] = c.x + c.y + c.z + c.w;
    __syncthreads();
    for (int off = 1; off < 256; off <<= 1) {
        int v = (t >= off) ? tmp[t - off] : 0;
        __syncthreads();
        tmp[t] += v;
        __syncthreads();
    }
    int4 rs;
    rs.x = blocksum[blockIdx.x] + ((t == 0) ? 0 : tmp[t - 1]);
    rs.y = rs.x + c.x;
    rs.z = rs.y + c.y;
    rs.w = rs.z + c.z;
    if (g + 3 < N) {
        *reinterpret_cast<int4*>(row_start + g) = rs;
        *reinterpret_cast<int4*>(cursor + g) = rs;
    } else {
        if (g + 0 < N) { row_start[g + 0] = rs.x; cursor[g + 0] = rs.x; }
        if (g + 1 < N) { row_start[g + 1] = rs.y; cursor[g + 1] = rs.y; }
        if (g + 2 < N) { row_start[g + 2] = rs.z; cursor[g + 2] = rs.z; }
        if (g + 3 < N) { row_start[g + 3] = rs.w; cursor[g + 3] = rs.w; }
    }
    if (blockIdx.x == 0 && t == 0) row_start[N] = total;
}

__global__ void scatter_kernel(const int* __restrict__ ei, int E, int N,
                               int* __restrict__ cursor, int* __restrict__ csr_src) {
    int t = blockIdx.x * blockDim.x + threadIdx.x;
    int e0 = t * 4;
    int EN = E + N;
    if (e0 >= EN) return;
    int s[4], d[4];
    if (((E & 3) == 0) && (e0 + 3 < E)) {
        int4 sv = *reinterpret_cast<const int4*>(ei + e0);
        int4 dv = *reinterpret_cast<const int4*>(ei + E + e0);
        s[0] = sv.x; s[1] = sv.y; s[2] = sv.z; s[3] = sv.w;
        d[0] = dv.x; d[1] = dv.y; d[2] = dv.z; d[3] = dv.w;
    } else {
#pragma unroll
        for (int k = 0; k < 4; ++k) {
            int e = e0 + k;
            if (e < E)       { s[k] = ei[e]; d[k] = ei[E + e]; }
            else if (e < EN) { s[k] = e - E; d[k] = s[k]; }
            else             { s[k] = 0; d[k] = -1; }
        }
    }
    int pos[4];
#pragma unroll
    for (int k = 0; k < 4; ++k)
        pos[k] = (d[k] >= 0) ? atomicAdd(&cursor[d[k]], 1) : 0;
#pragma unroll
    for (int k = 0; k < 4; ++k)
        if (d[k] >= 0) csr_src[pos[k]] = s[k];
}

// ------- layer-0 GEMM: C[N][128] = x[N][64] @ W0, fused als/ald epilogue -------

#define BM 32
#define BKK 32

__global__ __launch_bounds__(256) void gemm128_kernel(const float* __restrict__ A,
                                                      const float* __restrict__ W,
                                                      const float* __restrict__ avs,
                                                      const float* __restrict__ avd,
                                                      float* __restrict__ C,
                                                      float* __restrict__ als,
                                                      float* __restrict__ ald,
                                                      int N, int K) {
    __shared__ float xs[BM][BKK + 1];
    __shared__ float ws[BKK][128];
    __shared__ float red_s[BM][9];
    __shared__ float red_d[BM][9];
    int tid = threadIdx.x;
    int r  = tid & 31;
    int cg = tid >> 5;
    int row0 = blockIdx.x * BM;

    float acc[16];
#pragma unroll
    for (int j = 0; j < 16; ++j) acc[j] = 0.f;

    for (int kk = 0; kk < K; kk += BKK) {
        {
            int lr = tid >> 3, lc = (tid & 7) * 4;
            int gr = row0 + lr;
            float4 v = make_float4(0.f, 0.f, 0.f, 0.f);
            if (gr < N) v = *reinterpret_cast<const float4*>(A + (size_t)gr * K + kk + lc);
            xs[lr][lc + 0] = v.x; xs[lr][lc + 1] = v.y;
            xs[lr][lc + 2] = v.z; xs[lr][lc + 3] = v.w;
        }
        {
            int wr = tid >> 3, wc = (tid & 7) * 16;
            const float4* src = reinterpret_cast<const float4*>(W + (size_t)(kk + wr) * 128 + wc);
            float4* dst = reinterpret_cast<float4*>(&ws[wr][wc]);
#pragma unroll
            for (int i = 0; i < 4; ++i) dst[i] = src[i];
        }
        __syncthreads();
#pragma unroll 8
        for (int k = 0; k < BKK; ++k) {
            float xv = xs[r][k];
            const float4* wrow = reinterpret_cast<const float4*>(&ws[k][cg * 16]);
#pragma unroll
            for (int q = 0; q < 4; ++q) {
                float4 wv = wrow[q];
                acc[q * 4 + 0] += xv * wv.x;
                acc[q * 4 + 1] += xv * wv.y;
                acc[q * 4 + 2] += xv * wv.z;
                acc[q * 4 + 3] += xv * wv.w;
            }
        }
        __syncthreads();
    }
    int gr = row0 + r;
    if (gr < N) {
        float4* out = reinterpret_cast<float4*>(C + (size_t)gr * 128 + cg * 16);
#pragma unroll
        for (int q = 0; q < 4; ++q)
            out[q] = make_float4(acc[q * 4 + 0], acc[q * 4 + 1], acc[q * 4 + 2], acc[q * 4 + 3]);
    }
    {
        float ps = 0.f, pd = 0.f;
#pragma unroll
        for (int q = 0; q < 16; ++q) {
            float a = acc[q];
            ps += a * avs[cg * 16 + q];
            pd += a * avd[cg * 16 + q];
        }
        red_s[r][cg] = ps;
        red_d[r][cg] = pd;
        __syncthreads();
        if (gr < N) {
            if (cg < 4) {
                als[(size_t)gr * 4 + cg] = red_s[r][2 * cg] + red_s[r][2 * cg + 1];
            } else {
                int hd = cg - 4;
                ald[(size_t)gr * 4 + hd] = red_d[r][2 * hd] + red_d[r][2 * hd + 1];
            }
        }
    }
}

// ---------------- fused agg + GEMM layers ----------------
// Block = 32 nodes, 4 waves x 8 nodes sequential gather -> elu(agg+bias) into
// LDS xs[32][133] (stride 133: (5r+k)%32 conflict-free column reads), one
// barrier, then register-tiled GEMM reading W straight from global (64KB,
// L1/L2-hot, wave-broadcast addresses). als/ald epilogue for the next layer.

__device__ __forceinline__ float lrelu(float x) { return x > 0.f ? x : NEG_SLOPE * x; }

#define XSP 133

// gather one node v into o (valid in lanes 0-31); wave-synchronous helper
__device__ __forceinline__ void gather_node(const float* __restrict__ h,
                                            const float* __restrict__ als4,
                                            const float* __restrict__ ald4,
                                            const int* __restrict__ row_start,
                                            const int* __restrict__ csr_src,
                                            const float* __restrict__ bias,
                                            int v, int lane, float4& o) {
    int base = row_start[v], end = row_start[v + 1];
    int half = lane >> 5;
    int dim4 = (lane & 31) * 4;
    int hd2  = (lane & 31) >> 3;

    float aldh = ald4[(size_t)v * 4 + hd2];
    float alsh = als4[(size_t)v * 4 + hd2];
    float em = lrelu(alsh + aldh);          // self-loop logit as numeric shift
    const float* hdim = h + dim4;
    const float* alsb = als4 + hd2;

    float4 acc  = make_float4(0.f, 0.f, 0.f, 0.f);
    float4 acc2 = make_float4(0.f, 0.f, 0.f, 0.f);
    float ssum = 0.f, ssum2 = 0.f;

    int j = base + half;
    for (; j + 6 < end; j += 8) {
        int s0 = csr_src[j + 0];
        int s1 = csr_src[j + 2];
        int s2 = csr_src[j + 4];
        int s3 = csr_src[j + 6];
        float a0 = alsb[(size_t)s0 * 4];
        float a1 = alsb[(size_t)s1 * 4];
        float a2 = alsb[(size_t)s2 * 4];
        float a3 = alsb[(size_t)s3 * 4];
        float4 h0 = *reinterpret_cast<const float4*>(hdim + (size_t)s0 * 128);
        float4 h1 = *reinterpret_cast<const float4*>(hdim + (size_t)s1 * 128);
        float4 h2 = *reinterpret_cast<const float4*>(hdim + (size_t)s2 * 128);
        float4 h3 = *reinterpret_cast<const float4*>(hdim + (size_t)s3 * 128);
        float e0 = __expf(lrelu(a0 + aldh) - em);
        float e1 = __expf(lrelu(a1 + aldh) - em);
        float e2 = __expf(lrelu(a2 + aldh) - em);
        float e3 = __expf(lrelu(a3 + aldh) - em);
        ssum  += e0 + e2;
        ssum2 += e1 + e3;
        acc.x  += e0 * h0.x; acc.y  += e0 * h0.y; acc.z  += e0 * h0.z; acc.w  += e0 * h0.w;
        acc2.x += e1 * h1.x; acc2.y += e1 * h1.y; acc2.z += e1 * h1.z; acc2.w += e1 * h1.w;
        acc.x  += e2 * h2.x; acc.y  += e2 * h2.y; acc.z  += e2 * h2.z; acc.w  += e2 * h2.w;
        acc2.x += e3 * h3.x; acc2.y += e3 * h3.y; acc2.z += e3 * h3.z; acc2.w += e3 * h3.w;
    }
    for (; j < end; j += 2) {
        int s0 = csr_src[j];
        float a0 = alsb[(size_t)s0 * 4];
        float4 h0 = *reinterpret_cast<const float4*>(hdim + (size_t)s0 * 128);
        float e0 = __expf(lrelu(a0 + aldh) - em);
        ssum += e0;
        acc.x += e0 * h0.x; acc.y += e0 * h0.y; acc.z += e0 * h0.z; acc.w += e0 * h0.w;
    }
    acc.x += acc2.x; acc.y += acc2.y; acc.z += acc2.z; acc.w += acc2.w;
    ssum += ssum2;
    acc.x += __shfl_xor(acc.x, 32);
    acc.y += __shfl_xor(acc.y, 32);
    acc.z += __shfl_xor(acc.z, 32);
    acc.w += __shfl_xor(acc.w, 32);
    ssum  += __shfl_xor(ssum, 32);

    float inv = 1.0f / (ssum + 1e-16f);
    float4 bv = *reinterpret_cast<const float4*>(bias + dim4);
    o.x = acc.x * inv + bv.x;
    o.y = acc.y * inv + bv.y;
    o.z = acc.z * inv + bv.z;
    o.w = acc.w * inv + bv.w;
    o.x = o.x > 0.f ? o.x : expm1f(o.x);
    o.y = o.y > 0.f ? o.y : expm1f(o.y);
    o.z = o.z > 0.f ? o.z : expm1f(o.z);
    o.w = o.w > 0.f ? o.w : expm1f(o.w);
}

__global__ __launch_bounds__(256) void fused_layer_kernel(
        const float* __restrict__ h, const float* __restrict__ als4,
        const float* __restrict__ ald4, const int* __restrict__ row_start,
        const int* __restrict__ csr_src, const float* __restrict__ bias,
        const float* __restrict__ W, const float* __restrict__ avs,
        const float* __restrict__ avd, float* __restrict__ C,
        float* __restrict__ als_o, float* __restrict__ ald_o, int N) {
    __shared__ float xs[32][XSP];
    __shared__ float red_s[32][9];
    __shared__ float red_d[32][9];
    int tid = threadIdx.x;
    int wv = tid >> 6, lane = tid & 63;
    int row0 = blockIdx.x * 32;
    int dim4 = (lane & 31) * 4;

    // ---- gather phase: 8 nodes per wave ----
    for (int i = 0; i < 8; ++i) {
        int lr = wv * 8 + i;
        int v = row0 + lr;
        if (v < N) {
            float4 o;
            gather_node(h, als4, ald4, row_start, csr_src, bias, v, lane, o);
            if (lane < 32) {
                xs[lr][dim4 + 0] = o.x; xs[lr][dim4 + 1] = o.y;
                xs[lr][dim4 + 2] = o.z; xs[lr][dim4 + 3] = o.w;
            }
        } else if (lane < 32) {
            xs[lr][dim4 + 0] = 0.f; xs[lr][dim4 + 1] = 0.f;
            xs[lr][dim4 + 2] = 0.f; xs[lr][dim4 + 3] = 0.f;
        }
    }
    __syncthreads();

    // ---- GEMM phase: K=128, W direct from global (L1/L2-hot broadcast) ----
    int r = tid & 31, cg = tid >> 5;
    float acc[16];
#pragma unroll
    for (int q = 0; q < 16; ++q) acc[q] = 0.f;
    const float* Wc = W + cg * 16;
#pragma unroll 4
    for (int k = 0; k < 128; ++k) {
        float xv = xs[r][k];
        const float4* wrow = reinterpret_cast<const float4*>(Wc + (size_t)k * 128);
        float4 w0 = wrow[0], w1 = wrow[1], w2 = wrow[2], w3 = wrow[3];
        acc[0]  += xv * w0.x; acc[1]  += xv * w0.y; acc[2]  += xv * w0.z; acc[3]  += xv * w0.w;
        acc[4]  += xv * w1.x; acc[5]  += xv * w1.y; acc[6]  += xv * w1.z; acc[7]  += xv * w1.w;
        acc[8]  += xv * w2.x; acc[9]  += xv * w2.y; acc[10] += xv * w2.z; acc[11] += xv * w2.w;
        acc[12] += xv * w3.x; acc[13] += xv * w3.y; acc[14] += xv * w3.z; acc[15] += xv * w3.w;
    }
    int gr = row0 + r;
    if (gr < N) {
        float4* outp = reinterpret_cast<float4*>(C + (size_t)gr * 128 + cg * 16);
#pragma unroll
        for (int q = 0; q < 4; ++q)
            outp[q] = make_float4(acc[q * 4 + 0], acc[q * 4 + 1], acc[q * 4 + 2], acc[q * 4 + 3]);
    }
    // ---- als/ald epilogue for next layer ----
    {
        float ps = 0.f, pd = 0.f;
#pragma unroll
        for (int q = 0; q < 16; ++q) {
            float a = acc[q];
            ps += a * avs[cg * 16 + q];
            pd += a * avd[cg * 16 + q];
        }
        red_s[r][cg] = ps;
        red_d[r][cg] = pd;
        __syncthreads();
        if (gr < N) {
            if (cg < 4) {
                als_o[(size_t)gr * 4 + cg] = red_s[r][2 * cg] + red_s[r][2 * cg + 1];
            } else {
                int hd = cg - 4;
                ald_o[(size_t)gr * 4 + hd] = red_d[r][2 * hd] + red_d[r][2 * hd + 1];
            }
        }
    }
}

// fused layer-3: gather(layer-2 output) + GEMM 128->6 + als3/ald3
__global__ __launch_bounds__(256) void fused3_kernel(
        const float* __restrict__ h, const float* __restrict__ als4,
        const float* __restrict__ ald4, const int* __restrict__ row_start,
        const int* __restrict__ csr_src, const float* __restrict__ bias,
        const float* __restrict__ W3, const float* __restrict__ as3,
        const float* __restrict__ ad3, float* __restrict__ h3,
        float* __restrict__ als3, float* __restrict__ ald3, int N) {
    __shared__ float xs[32][XSP];
    __shared__ float hs[32][8];
    int tid = threadIdx.x;
    int wv = tid >> 6, lane = tid & 63;
    int row0 = blockIdx.x * 32;
    int dim4 = (lane & 31) * 4;

    for (int i = 0; i < 8; ++i) {
        int lr = wv * 8 + i;
        int v = row0 + lr;
        if (v < N) {
            float4 o;
            gather_node(h, als4, ald4, row_start, csr_src, bias, v, lane, o);
            if (lane < 32) {
                xs[lr][dim4 + 0] = o.x; xs[lr][dim4 + 1] = o.y;
                xs[lr][dim4 + 2] = o.z; xs[lr][dim4 + 3] = o.w;
            }
        } else if (lane < 32) {
            xs[lr][dim4 + 0] = 0.f; xs[lr][dim4 + 1] = 0.f;
            xs[lr][dim4 + 2] = 0.f; xs[lr][dim4 + 3] = 0.f;
        }
    }
    __syncthreads();

    int r = tid >> 3, q = tid & 7;
    if (q < 6) {
        float a = 0.f;
#pragma unroll 8
        for (int k = 0; k < 128; ++k)
            a += xs[r][k] * W3[(size_t)k * 6 + q];
        hs[r][q] = a;
        int v = row0 + r;
        if (v < N) h3[(size_t)v * 6 + q] = a;
    }
    __syncthreads();
    if (tid < 32) {
        int v = row0 + tid;
        if (v < N) {
            float s = 0.f, d = 0.f;
#pragma unroll
            for (int qq = 0; qq < 6; ++qq) {
                float a = hs[tid][qq];
                s += a * as3[qq];
                d += a * ad3[qq];
            }
            als3[v] = s;
            ald3[v] = d;
        }
    }
}

// final aggregation: single pass, self-loop shift, 2 independent edge chains
__global__ void agg3_kernel(const float* __restrict__ h3, const float* __restrict__ als3,
                            const float* __restrict__ ald3, const int* __restrict__ row_start,
                            const int* __restrict__ csr_src, const float* __restrict__ b3,
                            float* __restrict__ out, int N) {
    int v = blockIdx.x * blockDim.x + threadIdx.x;
    if (v >= N) return;
    int base = row_start[v], end = row_start[v + 1];
    float aldv = ald3[v];
    float em = lrelu(als3[v] + aldv);
    float ssum = 0.f;
    float acc[6] = {0.f, 0.f, 0.f, 0.f, 0.f, 0.f};
    float acc2[6] = {0.f, 0.f, 0.f, 0.f, 0.f, 0.f};
    int j = base;
    for (; j + 1 < end; j += 2) {
        int sa = csr_src[j], sb = csr_src[j + 1];
        float ea = __expf(lrelu(als3[sa] + aldv) - em);
        float eb = __expf(lrelu(als3[sb] + aldv) - em);
        ssum += ea + eb;
        const float* ha = h3 + (size_t)sa * 6;
        const float* hb = h3 + (size_t)sb * 6;
#pragma unroll
        for (int qq = 0; qq < 6; ++qq) acc[qq] += ea * ha[qq];
#pragma unroll
        for (int qq = 0; qq < 6; ++qq) acc2[qq] += eb * hb[qq];
    }
    if (j < end) {
        int sa = csr_src[j];
        float ea = __expf(lrelu(als3[sa] + aldv) - em);
        ssum += ea;
        const float* ha = h3 + (size_t)sa * 6;
#pragma unroll
        for (int qq = 0; qq < 6; ++qq) acc[qq] += ea * ha[qq];
    }
    float inv = 1.f / (ssum + 1e-16f);
#pragma unroll
    for (int qq = 0; qq < 6; ++qq) out[(size_t)v * 6 + qq] = (acc[qq] + acc2[qq]) * inv + b3[qq];
}

// ---------------- launch ----------------

extern "C" void kernel_launch(void* const* d_in, const int* in_sizes, int n_in,
                              void* d_out, int out_size, void* d_ws, size_t ws_size,
                              hipStream_t stream) {
    const float* x    = (const float*)d_in[0];
    const int*   ei   = (const int*)d_in[1];
    const float* W0   = (const float*)d_in[3];
    const float* as0  = (const float*)d_in[4];
    const float* ad0  = (const float*)d_in[5];
    const float* b0   = (const float*)d_in[6];
    const float* W1   = (const float*)d_in[7];
    const float* as1  = (const float*)d_in[8];
    const float* ad1  = (const float*)d_in[9];
    const float* b1   = (const float*)d_in[10];
    const float* W2   = (const float*)d_in[11];
    const float* as2  = (const float*)d_in[12];
    const float* ad2  = (const float*)d_in[13];
    const float* b2   = (const float*)d_in[14];
    const float* W3   = (const float*)d_in[15];
    const float* as3  = (const float*)d_in[16];
    const float* ad3  = (const float*)d_in[17];
    const float* b3   = (const float*)d_in[18];
    float* out = (float*)d_out;

    int N = in_sizes[0] / IN_CH;
    int E = in_sizes[1] / 2;
    int EN = E + N;

    char* p = (char*)d_ws;
    auto alloc = [&](size_t bytes) {
        char* q = p;
        p += (bytes + 255) & ~(size_t)255;
        return q;
    };
    float* hA   = (float*)alloc((size_t)N * 128 * 4);   // h0 / h2
    float* hB   = (float*)alloc((size_t)N * 128 * 4);   // h1
    float* alsA = (float*)alloc((size_t)N * 4 * 4);
    float* aldA = (float*)alloc((size_t)N * 4 * 4);
    float* alsB = (float*)alloc((size_t)N * 4 * 4);
    float* aldB = (float*)alloc((size_t)N * 4 * 4);
    float* h3   = (float*)alloc((size_t)N * 6 * 4);
    float* als3 = (float*)alloc((size_t)N * 4);
    float* ald3 = (float*)alloc((size_t)N * 4);
    int* row_start = (int*)alloc((size_t)(N + 1) * 4);
    int* cursor    = (int*)alloc((size_t)N * 4);
    int* csr_src   = (int*)alloc((size_t)EN * 4);
    int* blocksum  = (int*)alloc((size_t)4096 * 4);
    (void)ws_size; (void)n_in; (void)out_size;

    // ---- build CSR by dst ----
    hipMemsetAsync(cursor, 0, (size_t)N * 4, stream);
    int ethreads = (EN + 3) / 4;
    hist_kernel<<<(ethreads + 255) / 256, 256, 0, stream>>>(ei, E, N, cursor);
    int nb = (N + SCAN_ELEMS - 1) / SCAN_ELEMS;
    scan_partial<<<nb, 256, 0, stream>>>(cursor, N, blocksum);
    scan_sums<<<1, 256, 0, stream>>>(blocksum, nb);
    scan_apply<<<nb, 256, 0, stream>>>(cursor, N, EN, blocksum, row_start, cursor);
    scatter_kernel<<<(ethreads + 255) / 256, 256, 0, stream>>>(ei, E, N, cursor, csr_src);

    int gemm_grid  = (N + BM - 1) / BM;
    int fused_grid = (N + 31) / 32;
    int n_grid     = (N + 255) / 256;

    // layer 0 (dense): x @ W0 -> h0, als0, ald0
    gemm128_kernel<<<gemm_grid, 256, 0, stream>>>(x, W0, as0, ad0, hA, alsA, aldA, N, 64);
    // layer 1: agg(h0) -> elu -> @W1 -> h1, als1, ald1
    fused_layer_kernel<<<fused_grid, 256, 0, stream>>>(hA, alsA, aldA, row_start, csr_src,
                                                       b0, W1, as1, ad1, hB, alsB, aldB, N);
    // layer 2: agg(h1) -> elu -> @W2 -> h2, als2, ald2
    fused_layer_kernel<<<fused_grid, 256, 0, stream>>>(hB, alsB, aldB, row_start, csr_src,
                                                       b1, W2, as2, ad2, hA, alsA, aldA, N);
    // layer 3: agg(h2) -> elu -> @W3 -> h3, als3, ald3
    fused3_kernel<<<fused_grid, 256, 0, stream>>>(hA, alsA, aldA, row_start, csr_src,
                                                  b2, W3, as3, ad3, h3, als3, ald3, N);
    // final aggregation
    agg3_kernel<<<n_grid, 256, 0, stream>>>(h3, als3, ald3, row_start, csr_src, b3, out, N);
}

// Round 8
// 647.443 us; speedup vs baseline: 1.5169x; 1.5169x over previous
//
#include <hip/hip_runtime.h>
#include <hip/hip_bf16.h>
#include <hip/hip_fp16.h>

#define IN_CH 64
#define HID 32
#define HEADS 4
#define OUT_CH 6
#define NEG_SLOPE 0.2f

// ---------------- preprocessing: build dst-CSR ----------------

__global__ void hist_kernel(const int* __restrict__ ei, int E, int N, int* __restrict__ cnt) {
    int t = blockIdx.x * blockDim.x + threadIdx.x;
    int e0 = t * 4;
    int EN = E + N;
    if (e0 >= EN) return;
    int d[4];
    if (((E & 3) == 0) && (e0 + 3 < E)) {
        int4 dv = *reinterpret_cast<const int4*>(ei + E + e0);
        d[0] = dv.x; d[1] = dv.y; d[2] = dv.z; d[3] = dv.w;
    } else {
#pragma unroll
        for (int k = 0; k < 4; ++k) {
            int e = e0 + k;
            d[k] = (e < E) ? ei[E + e] : (e < EN ? e - E : -1);
        }
    }
#pragma unroll
    for (int k = 0; k < 4; ++k)
        if (d[k] >= 0) atomicAdd(&cnt[d[k]], 1);
}

#define SCAN_ELEMS 1024

__global__ __launch_bounds__(256) void scan_partial(const int* __restrict__ cnt, int N,
                                                    int* __restrict__ blocksum) {
    __shared__ int red[256];
    int t = threadIdx.x;
    int b0 = blockIdx.x * SCAN_ELEMS;
    int sum = 0;
#pragma unroll
    for (int i = 0; i < SCAN_ELEMS / 256; ++i) {
        int g = b0 + t + i * 256;
        sum += (g < N) ? cnt[g] : 0;
    }
    red[t] = sum;
    __syncthreads();
    for (int off = 128; off; off >>= 1) {
        if (t < off) red[t] += red[t + off];
        __syncthreads();
    }
    if (t == 0) blocksum[blockIdx.x] = red[0];
}

__global__ __launch_bounds__(256) void scan_sums(int* __restrict__ blocksum, int nb) {
    __shared__ int tmp[256];
    int t = threadIdx.x;
    int chunk = (nb + 255) >> 8;
    int s0 = t * chunk, s1 = min(s0 + chunk, nb);
    int sum = 0;
    for (int i = s0; i < s1; ++i) sum += blocksum[i];
    tmp[t] = sum;
    __syncthreads();
    for (int off = 1; off < 256; off <<= 1) {
        int v = (t >= off) ? tmp[t - off] : 0;
        __syncthreads();
        tmp[t] += v;
        __syncthreads();
    }
    int run = (t == 0) ? 0 : tmp[t - 1];
    for (int i = s0; i < s1; ++i) {
        int c = blocksum[i];
        blocksum[i] = run;
        run += c;
    }
}

__global__ __launch_bounds__(256) void scan_apply(const int* __restrict__ cnt, int N, int total,
                                                  const int* __restrict__ blocksum,
                                                  int* __restrict__ row_start,
                                                  int* __restrict__ cursor) {
    __shared__ int tmp[256];
    int t = threadIdx.x;
    int g = blockIdx.x * SCAN_ELEMS + t * 4;
    int4 c = make_int4(0, 0, 0, 0);
    if (g + 3 < N) {
        c = *reinterpret_cast<const int4*>(cnt + g);
    } else {
        if (g + 0 < N) c.x = cnt[g + 0];
        if (g + 1 < N) c.y = cnt[g + 1];
        if (g + 2 < N) c.z = cnt[g + 2];
        if (g + 3 < N) c.w = cnt[g + 3];
    }
    tmp[t] = c.x + c.y + c.z + c.w;
    __syncthreads();
    for (int off = 1; off < 256; off <<= 1) {
        int v = (t >= off) ? tmp[t - off] : 0;
        __syncthreads();
        tmp[t] += v;
        __syncthreads();
    }
    int4 rs;
    rs.x = blocksum[blockIdx.x] + ((t == 0) ? 0 : tmp[t - 1]);
    rs.y = rs.x + c.x;
    rs.z = rs.y + c.y;
    rs.w = rs.z + c.z;
    if (g + 3 < N) {
        *reinterpret_cast<int4*>(row_start + g) = rs;
        *reinterpret_cast<int4*>(cursor + g) = rs;
    } else {
        if (g + 0 < N) { row_start[g + 0] = rs.x; cursor[g + 0] = rs.x; }
        if (g + 1 < N) { row_start[g + 1] = rs.y; cursor[g + 1] = rs.y; }
        if (g + 2 < N) { row_start[g + 2] = rs.z; cursor[g + 2] = rs.z; }
        if (g + 3 < N) { row_start[g + 3] = rs.w; cursor[g + 3] = rs.w; }
    }
    if (blockIdx.x == 0 && t == 0) row_start[N] = total;
}

__global__ void scatter_kernel(const int* __restrict__ ei, int E, int N,
                               int* __restrict__ cursor, int* __restrict__ csr_src) {
    int t = blockIdx.x * blockDim.x + threadIdx.x;
    int e0 = t * 4;
    int EN = E + N;
    if (e0 >= EN) return;
    int s[4], d[4];
    if (((E & 3) == 0) && (e0 + 3 < E)) {
        int4 sv = *reinterpret_cast<const int4*>(ei + e0);
        int4 dv = *reinterpret_cast<const int4*>(ei + E + e0);
        s[0] = sv.x; s[1] = sv.y; s[2] = sv.z; s[3] = sv.w;
        d[0] = dv.x; d[1] = dv.y; d[2] = dv.z; d[3] = dv.w;
    } else {
#pragma unroll
        for (int k = 0; k < 4; ++k) {
            int e = e0 + k;
            if (e < E)       { s[k] = ei[e]; d[k] = ei[E + e]; }
            else if (e < EN) { s[k] = e - E; d[k] = s[k]; }
            else             { s[k] = 0; d[k] = -1; }
        }
    }
    int pos[4];
#pragma unroll
    for (int k = 0; k < 4; ++k)
        pos[k] = (d[k] >= 0) ? atomicAdd(&cursor[d[k]], 1) : 0;
#pragma unroll
    for (int k = 0; k < 4; ++k)
        if (d[k] >= 0) csr_src[pos[k]] = s[k];
}

// ------- GEMM: C[N][128](fp16) = A[N][K] @ W[K][128], fused als/ald -------

#define BM 32
#define BKK 32

__global__ __launch_bounds__(256) void gemm128_kernel(const float* __restrict__ A,
                                                      const float* __restrict__ W,
                                                      const float* __restrict__ avs,
                                                      const float* __restrict__ avd,
                                                      __half* __restrict__ C,
                                                      float* __restrict__ als,
                                                      float* __restrict__ ald,
                                                      int N, int K) {
    __shared__ float xs[BM][BKK + 1];
    __shared__ float ws[BKK][128];
    __shared__ float red_s[BM][9];
    __shared__ float red_d[BM][9];
    int tid = threadIdx.x;
    int r  = tid & 31;
    int cg = tid >> 5;
    int row0 = blockIdx.x * BM;

    float acc[16];
#pragma unroll
    for (int j = 0; j < 16; ++j) acc[j] = 0.f;

    for (int kk = 0; kk < K; kk += BKK) {
        {
            int lr = tid >> 3, lc = (tid & 7) * 4;
            int gr = row0 + lr;
            float4 v = make_float4(0.f, 0.f, 0.f, 0.f);
            if (gr < N) v = *reinterpret_cast<const float4*>(A + (size_t)gr * K + kk + lc);
            xs[lr][lc + 0] = v.x; xs[lr][lc + 1] = v.y;
            xs[lr][lc + 2] = v.z; xs[lr][lc + 3] = v.w;
        }
        {
            int wr = tid >> 3, wc = (tid & 7) * 16;
            const float4* src = reinterpret_cast<const float4*>(W + (size_t)(kk + wr) * 128 + wc);
            float4* dst = reinterpret_cast<float4*>(&ws[wr][wc]);
#pragma unroll
            for (int i = 0; i < 4; ++i) dst[i] = src[i];
        }
        __syncthreads();
#pragma unroll 8
        for (int k = 0; k < BKK; ++k) {
            float xv = xs[r][k];
            const float4* wrow = reinterpret_cast<const float4*>(&ws[k][cg * 16]);
#pragma unroll
            for (int q = 0; q < 4; ++q) {
                float4 wv = wrow[q];
                acc[q * 4 + 0] += xv * wv.x;
                acc[q * 4 + 1] += xv * wv.y;
                acc[q * 4 + 2] += xv * wv.z;
                acc[q * 4 + 3] += xv * wv.w;
            }
        }
        __syncthreads();
    }
    int gr = row0 + r;
    if (gr < N) {
        __half2* outp = reinterpret_cast<__half2*>(C + (size_t)gr * 128 + cg * 16);
#pragma unroll
        for (int q = 0; q < 8; ++q)
            outp[q] = __float22half2_rn(make_float2(acc[q * 2], acc[q * 2 + 1]));
    }
    // als/ald from fp32 accumulators (no quantization on the logit path)
    {
        float ps = 0.f, pd = 0.f;
#pragma unroll
        for (int q = 0; q < 16; ++q) {
            float a = acc[q];
            ps += a * avs[cg * 16 + q];
            pd += a * avd[cg * 16 + q];
        }
        red_s[r][cg] = ps;
        red_d[r][cg] = pd;
        __syncthreads();
        if (gr < N) {
            if (cg < 4) {
                als[(size_t)gr * 4 + cg] = red_s[r][2 * cg] + red_s[r][2 * cg + 1];
            } else {
                int hd = cg - 4;
                ald[(size_t)gr * 4 + hd] = red_d[r][2 * hd] + red_d[r][2 * hd + 1];
            }
        }
    }
}

// ---------------- wave-per-node aggregation (layers 0-2), fp16 h ----------------
// Flat single-stream loop; half-wave lanes share an edge (uniform csr/als
// broadcasts, redundant exp); each lane owns a 4-dim slice -> one 8B uint2
// load per edge row slice (32 lanes x 8B = 256B row). Unroll x4 per half.
// Softmax shift = self-loop logit.

__device__ __forceinline__ float lrelu(float x) { return x > 0.f ? x : NEG_SLOPE * x; }

__global__ __launch_bounds__(256) void agg_kernel(const __half* __restrict__ h,
                                                  const float* __restrict__ als4,
                                                  const float* __restrict__ ald4,
                                                  const int* __restrict__ row_start,
                                                  const int* __restrict__ csr_src,
                                                  const float* __restrict__ bias,
                                                  float* __restrict__ xout,
                                                  int N, int applyElu) {
    int v = (int)((blockIdx.x * blockDim.x + threadIdx.x) >> 6);
    int lane = threadIdx.x & 63;
    if (v >= N) return;
    int base = row_start[v], end = row_start[v + 1];

    int half_ = lane >> 5;         // 0: even edges, 1: odd edges
    int dim4 = (lane & 31) * 4;    // 4-dim slice of the 128-dim row
    int hd2  = (lane & 31) >> 3;   // head of this slice

    float aldh = ald4[(size_t)v * 4 + hd2];
    float alsh = als4[(size_t)v * 4 + hd2];
    float em = lrelu(alsh + aldh);
    const __half* hdim = h + dim4;
    const float* alsb = als4 + hd2;

    float4 acc  = make_float4(0.f, 0.f, 0.f, 0.f);
    float4 acc2 = make_float4(0.f, 0.f, 0.f, 0.f);
    float ssum = 0.f, ssum2 = 0.f;

    int j = base + half_;
    for (; j + 6 < end; j += 8) {
        int s0 = csr_src[j + 0];
        int s1 = csr_src[j + 2];
        int s2 = csr_src[j + 4];
        int s3 = csr_src[j + 6];
        float a0 = alsb[(size_t)s0 * 4];
        float a1 = alsb[(size_t)s1 * 4];
        float a2 = alsb[(size_t)s2 * 4];
        float a3 = alsb[(size_t)s3 * 4];
        uint2 r0 = *reinterpret_cast<const uint2*>(hdim + (size_t)s0 * 128);
        uint2 r1 = *reinterpret_cast<const uint2*>(hdim + (size_t)s1 * 128);
        uint2 r2 = *reinterpret_cast<const uint2*>(hdim + (size_t)s2 * 128);
        uint2 r3 = *reinterpret_cast<const uint2*>(hdim + (size_t)s3 * 128);
        float e0 = __expf(lrelu(a0 + aldh) - em);
        float e1 = __expf(lrelu(a1 + aldh) - em);
        float e2 = __expf(lrelu(a2 + aldh) - em);
        float e3 = __expf(lrelu(a3 + aldh) - em);
        ssum  += e0 + e2;
        ssum2 += e1 + e3;
        float2 f0a = __half22float2(*reinterpret_cast<__half2*>(&r0.x));
        float2 f0b = __half22float2(*reinterpret_cast<__half2*>(&r0.y));
        float2 f1a = __half22float2(*reinterpret_cast<__half2*>(&r1.x));
        float2 f1b = __half22float2(*reinterpret_cast<__half2*>(&r1.y));
        float2 f2a = __half22float2(*reinterpret_cast<__half2*>(&r2.x));
        float2 f2b = __half22float2(*reinterpret_cast<__half2*>(&r2.y));
        float2 f3a = __half22float2(*reinterpret_cast<__half2*>(&r3.x));
        float2 f3b = __half22float2(*reinterpret_cast<__half2*>(&r3.y));
        acc.x  += e0 * f0a.x; acc.y  += e0 * f0a.y; acc.z  += e0 * f0b.x; acc.w  += e0 * f0b.y;
        acc2.x += e1 * f1a.x; acc2.y += e1 * f1a.y; acc2.z += e1 * f1b.x; acc2.w += e1 * f1b.y;
        acc.x  += e2 * f2a.x; acc.y  += e2 * f2a.y; acc.z  += e2 * f2b.x; acc.w  += e2 * f2b.y;
        acc2.x += e3 * f3a.x; acc2.y += e3 * f3a.y; acc2.z += e3 * f3b.x; acc2.w += e3 * f3b.y;
    }
    for (; j < end; j += 2) {
        int s0 = csr_src[j];
        float a0 = alsb[(size_t)s0 * 4];
        uint2 r0 = *reinterpret_cast<const uint2*>(hdim + (size_t)s0 * 128);
        float e0 = __expf(lrelu(a0 + aldh) - em);
        ssum += e0;
        float2 f0a = __half22float2(*reinterpret_cast<__half2*>(&r0.x));
        float2 f0b = __half22float2(*reinterpret_cast<__half2*>(&r0.y));
        acc.x += e0 * f0a.x; acc.y += e0 * f0a.y; acc.z += e0 * f0b.x; acc.w += e0 * f0b.y;
    }
    acc.x += acc2.x; acc.y += acc2.y; acc.z += acc2.z; acc.w += acc2.w;
    ssum += ssum2;
    acc.x += __shfl_xor(acc.x, 32);
    acc.y += __shfl_xor(acc.y, 32);
    acc.z += __shfl_xor(acc.z, 32);
    acc.w += __shfl_xor(acc.w, 32);
    ssum  += __shfl_xor(ssum, 32);

    if (lane < 32) {
        float inv = 1.0f / (ssum + 1e-16f);
        float4 bv = *reinterpret_cast<const float4*>(bias + dim4);
        float4 o;
        o.x = acc.x * inv + bv.x;
        o.y = acc.y * inv + bv.y;
        o.z = acc.z * inv + bv.z;
        o.w = acc.w * inv + bv.w;
        if (applyElu) {
            o.x = o.x > 0.f ? o.x : expm1f(o.x);
            o.y = o.y > 0.f ? o.y : expm1f(o.y);
            o.z = o.z > 0.f ? o.z : expm1f(o.z);
            o.w = o.w > 0.f ? o.w : expm1f(o.w);
        }
        *reinterpret_cast<float4*>(xout + (size_t)v * 128 + dim4) = o;
    }
}

// ---------------- layer 3: GEMM [N,128]x[128,6] with fused al ----------------

__global__ void gemm3_kernel(const float* __restrict__ x, const float* __restrict__ W,
                             const float* __restrict__ as3, const float* __restrict__ ad3,
                             float* __restrict__ h3, float* __restrict__ als3,
                             float* __restrict__ ald3, int N) {
    int n = blockIdx.x * blockDim.x + threadIdx.x;
    if (n >= N) return;
    float acc[6] = {0.f, 0.f, 0.f, 0.f, 0.f, 0.f};
    const float4* xp = reinterpret_cast<const float4*>(x + (size_t)n * 128);
#pragma unroll 4
    for (int k4 = 0; k4 < 32; ++k4) {
        float4 xv = xp[k4];
        const float* w0 = W + (size_t)(k4 * 4) * 6;
#pragma unroll
        for (int j = 0; j < 6; ++j)
            acc[j] += xv.x * w0[j] + xv.y * w0[6 + j] + xv.z * w0[12 + j] + xv.w * w0[18 + j];
    }
    float s = 0.f, d = 0.f;
#pragma unroll
    for (int j = 0; j < 6; ++j) {
        s += acc[j] * as3[j];
        d += acc[j] * ad3[j];
        h3[(size_t)n * 6 + j] = acc[j];
    }
    als3[n] = s;
    ald3[n] = d;
}

__global__ void agg3_kernel(const float* __restrict__ h3, const float* __restrict__ als3,
                            const float* __restrict__ ald3, const int* __restrict__ row_start,
                            const int* __restrict__ csr_src, const float* __restrict__ b3,
                            float* __restrict__ out, int N) {
    int v = blockIdx.x * blockDim.x + threadIdx.x;
    if (v >= N) return;
    int base = row_start[v], end = row_start[v + 1];
    float aldv = ald3[v];
    float em = lrelu(als3[v] + aldv);
    float ssum = 0.f;
    float acc[6] = {0.f, 0.f, 0.f, 0.f, 0.f, 0.f};
    float acc2[6] = {0.f, 0.f, 0.f, 0.f, 0.f, 0.f};
    int j = base;
    for (; j + 1 < end; j += 2) {
        int sa = csr_src[j], sb = csr_src[j + 1];
        float ea = __expf(lrelu(als3[sa] + aldv) - em);
        float eb = __expf(lrelu(als3[sb] + aldv) - em);
        ssum += ea + eb;
        const float* ha = h3 + (size_t)sa * 6;
        const float* hb = h3 + (size_t)sb * 6;
#pragma unroll
        for (int q = 0; q < 6; ++q) acc[q] += ea * ha[q];
#pragma unroll
        for (int q = 0; q < 6; ++q) acc2[q] += eb * hb[q];
    }
    if (j < end) {
        int sa = csr_src[j];
        float ea = __expf(lrelu(als3[sa] + aldv) - em);
        ssum += ea;
        const float* ha = h3 + (size_t)sa * 6;
#pragma unroll
        for (int q = 0; q < 6; ++q) acc[q] += ea * ha[q];
    }
    float inv = 1.f / (ssum + 1e-16f);
#pragma unroll
    for (int q = 0; q < 6; ++q) out[(size_t)v * 6 + q] = (acc[q] + acc2[q]) * inv + b3[q];
}

// ---------------- launch ----------------

extern "C" void kernel_launch(void* const* d_in, const int* in_sizes, int n_in,
                              void* d_out, int out_size, void* d_ws, size_t ws_size,
                              hipStream_t stream) {
    const float* x    = (const float*)d_in[0];
    const int*   ei   = (const int*)d_in[1];
    const float* W0   = (const float*)d_in[3];
    const float* as0  = (const float*)d_in[4];
    const float* ad0  = (const float*)d_in[5];
    const float* b0   = (const float*)d_in[6];
    const float* W1   = (const float*)d_in[7];
    const float* as1  = (const float*)d_in[8];
    const float* ad1  = (const float*)d_in[9];
    const float* b1   = (const float*)d_in[10];
    const float* W2   = (const float*)d_in[11];
    const float* as2  = (const float*)d_in[12];
    const float* ad2  = (const float*)d_in[13];
    const float* b2   = (const float*)d_in[14];
    const float* W3   = (const float*)d_in[15];
    const float* as3  = (const float*)d_in[16];
    const float* ad3  = (const float*)d_in[17];
    const float* b3   = (const float*)d_in[18];
    float* out = (float*)d_out;

    int N = in_sizes[0] / IN_CH;
    int E = in_sizes[1] / 2;
    int EN = E + N;

    char* p = (char*)d_ws;
    auto alloc = [&](size_t bytes) {
        char* q = p;
        p += (bytes + 255) & ~(size_t)255;
        return q;
    };
    __half* hbuf = (__half*)alloc((size_t)N * 128 * 2);   // fp16 h (gather payload)
    float* xA   = (float*)alloc((size_t)N * 128 * 4);
    float* xB   = (float*)alloc((size_t)N * 128 * 4);
    float* als  = (float*)alloc((size_t)N * 4 * 4);
    float* ald  = (float*)alloc((size_t)N * 4 * 4);
    float* h3   = (float*)alloc((size_t)N * 6 * 4);
    float* als3 = (float*)alloc((size_t)N * 4);
    float* ald3 = (float*)alloc((size_t)N * 4);
    int* row_start = (int*)alloc((size_t)(N + 1) * 4);
    int* cursor    = (int*)alloc((size_t)N * 4);
    int* csr_src   = (int*)alloc((size_t)EN * 4);
    int* blocksum  = (int*)alloc((size_t)4096 * 4);
    (void)ws_size; (void)n_in; (void)out_size;

    // ---- build CSR by dst ----
    hipMemsetAsync(cursor, 0, (size_t)N * 4, stream);
    int ethreads = (EN + 3) / 4;
    hist_kernel<<<(ethreads + 255) / 256, 256, 0, stream>>>(ei, E, N, cursor);
    int nb = (N + SCAN_ELEMS - 1) / SCAN_ELEMS;
    scan_partial<<<nb, 256, 0, stream>>>(cursor, N, blocksum);
    scan_sums<<<1, 256, 0, stream>>>(blocksum, nb);
    scan_apply<<<nb, 256, 0, stream>>>(cursor, N, EN, blocksum, row_start, cursor);
    scatter_kernel<<<(ethreads + 255) / 256, 256, 0, stream>>>(ei, E, N, cursor, csr_src);

    int gemm_grid = (N + BM - 1) / BM;
    int agg_grid  = (N + 3) / 4;
    int n_grid    = (N + 255) / 256;

    // ---- layer 0 ----
    gemm128_kernel<<<gemm_grid, 256, 0, stream>>>(x, W0, as0, ad0, hbuf, als, ald, N, 64);
    agg_kernel<<<agg_grid, 256, 0, stream>>>(hbuf, als, ald, row_start, csr_src, b0, xA, N, 1);

    // ---- layer 1 ----
    gemm128_kernel<<<gemm_grid, 256, 0, stream>>>(xA, W1, as1, ad1, hbuf, als, ald, N, 128);
    agg_kernel<<<agg_grid, 256, 0, stream>>>(hbuf, als, ald, row_start, csr_src, b1, xB, N, 1);

    // ---- layer 2 ----
    gemm128_kernel<<<gemm_grid, 256, 0, stream>>>(xB, W2, as2, ad2, hbuf, als, ald, N, 128);
    agg_kernel<<<agg_grid, 256, 0, stream>>>(hbuf, als, ald, row_start, csr_src, b2, xA, N, 1);

    // ---- layer 3 ----
    gemm3_kernel<<<n_grid, 256, 0, stream>>>(xA, W3, as3, ad3, h3, als3, ald3, N);
    agg3_kernel<<<n_grid, 256, 0, stream>>>(h3, als3, ald3, row_start, csr_src, b3, out, N);
}

// Round 9
// 521.510 us; speedup vs baseline: 1.8832x; 1.2415x over previous
//
#include <hip/hip_runtime.h>
#include <hip/hip_bf16.h>
#include <hip/hip_fp16.h>

#define IN_CH 64
#define HID 32
#define HEADS 4
#define OUT_CH 6
#define NEG_SLOPE 0.2f

// ============== CSR build: bucket-partitioned, LDS-atomic only ==============
// bucket = dst >> 8 (256 dsts/bucket). NB = ceil(N/256) <= 512 assumed.
// PBLK = 256 partition blocks; exact per-(bucket,block) slot reservation via
// scans -> conflict-free placement, all writes line-local, zero global atomics.

#define PBLK 256
#define CAP 6144   // LDS staging capacity per bucket (mean 4352, sd 64)

// Pass A: per-block per-bucket counts
__global__ __launch_bounds__(256) void part_count(const int* __restrict__ ei, int E, int EN,
                                                  int NB, int epb, int* __restrict__ counts) {
    __shared__ int cnt[512];
    int b = blockIdx.x, t = threadIdx.x;
    for (int i = t; i < NB; i += 256) cnt[i] = 0;
    __syncthreads();
    int e0 = b * epb;
    int e1 = min(e0 + epb, EN);
    for (int e = e0 + t; e < e1; e += 256) {
        int d = (e < E) ? ei[E + e] : (e - E);
        atomicAdd(&cnt[d >> 8], 1);
    }
    __syncthreads();
    for (int i = t; i < NB; i += 256) counts[(size_t)i * PBLK + b] = cnt[i];
}

// Pass B1: bucket totals
__global__ __launch_bounds__(256) void bucket_tot(const int* __restrict__ counts,
                                                  int* __restrict__ btot) {
    __shared__ int red[256];
    int k = blockIdx.x, t = threadIdx.x;
    red[t] = counts[(size_t)k * PBLK + t];
    __syncthreads();
    for (int off = 128; off; off >>= 1) {
        if (t < off) red[t] += red[t + off];
        __syncthreads();
    }
    if (t == 0) btot[k] = red[0];
}

// Pass B2: exclusive scan of bucket totals -> bstart[0..NB]
__global__ __launch_bounds__(256) void bucket_scan(const int* __restrict__ btot, int NB, int EN,
                                                   int* __restrict__ bstart) {
    __shared__ int tmp[256];
    int t = threadIdx.x;
    int chunk = (NB + 255) >> 8;
    int s0 = t * chunk, s1 = min(s0 + chunk, NB);
    int sum = 0;
    for (int i = s0; i < s1; ++i) sum += btot[i];
    tmp[t] = sum;
    __syncthreads();
    for (int off = 1; off < 256; off <<= 1) {
        int v = (t >= off) ? tmp[t - off] : 0;
        __syncthreads();
        tmp[t] += v;
        __syncthreads();
    }
    int run = (t == 0) ? 0 : tmp[t - 1];
    for (int i = s0; i < s1; ++i) {
        int c = btot[i];
        bstart[i] = run;
        run += c;
    }
    if (t == 255) bstart[NB] = EN;
}

// Pass B3: per-bucket exclusive scan over blocks + bstart -> base (in place)
__global__ __launch_bounds__(256) void bucket_base(int* __restrict__ counts,
                                                   const int* __restrict__ bstart) {
    __shared__ int sc[256];
    int k = blockIdx.x, t = threadIdx.x;
    int v = counts[(size_t)k * PBLK + t];
    sc[t] = v;
    __syncthreads();
    for (int off = 1; off < 256; off <<= 1) {
        int u = (t >= off) ? sc[t - off] : 0;
        __syncthreads();
        sc[t] += u;
        __syncthreads();
    }
    counts[(size_t)k * PBLK + t] = bstart[k] + sc[t] - v;   // exclusive + base
}

// Pass C: partition edges into ebuf by bucket (reserved slots, LDS cursors)
__global__ __launch_bounds__(256) void part_scatter(const int* __restrict__ ei, int E, int EN,
                                                    int NB, int epb,
                                                    const int* __restrict__ base,
                                                    int2* __restrict__ ebuf) {
    __shared__ int cur[512];
    int b = blockIdx.x, t = threadIdx.x;
    for (int i = t; i < NB; i += 256) cur[i] = base[(size_t)i * PBLK + b];
    __syncthreads();
    int e0 = b * epb;
    int e1 = min(e0 + epb, EN);
    for (int e = e0 + t; e < e1; e += 256) {
        int s, d;
        if (e < E) { s = ei[e]; d = ei[E + e]; }
        else       { s = e - E; d = s; }
        int slot = atomicAdd(&cur[d >> 8], 1);
        ebuf[slot] = make_int2(s, d & 255);   // local dst within bucket
    }
}

// Pass D: per-bucket local CSR: count -> scan -> row_start -> LDS-stage -> coalesced out
__global__ __launch_bounds__(256) void bucket_csr(const int2* __restrict__ ebuf,
                                                  const int* __restrict__ bstart,
                                                  int NB, int N, int EN,
                                                  int* __restrict__ row_start,
                                                  int* __restrict__ csr_src) {
    __shared__ int cnt[256];
    __shared__ int sc[256];
    __shared__ int stage[CAP];
    int k = blockIdx.x, t = threadIdx.x;
    int s0 = bstart[k], s1 = bstart[k + 1];
    int len = s1 - s0;
    cnt[t] = 0;
    __syncthreads();
    for (int i = t; i < len; i += 256) atomicAdd(&cnt[ebuf[s0 + i].y], 1);
    __syncthreads();
    int v = cnt[t];
    sc[t] = v;
    __syncthreads();
    for (int off = 1; off < 256; off <<= 1) {
        int u = (t >= off) ? sc[t - off] : 0;
        __syncthreads();
        sc[t] += u;
        __syncthreads();
    }
    int excl = sc[t] - v;
    int g = (k << 8) + t;
    if (g < N) row_start[g] = s0 + excl;
    if (k == NB - 1 && t == 0) row_start[N] = EN;
    bool fits = (len <= CAP);
    cnt[t] = fits ? excl : s0 + excl;   // reuse as cursor
    __syncthreads();
    if (fits) {
        for (int i = t; i < len; i += 256) {
            int2 e = ebuf[s0 + i];
            int slot = atomicAdd(&cnt[e.y], 1);
            stage[slot] = e.x;
        }
        __syncthreads();
        for (int i = t; i < len; i += 256) csr_src[s0 + i] = stage[i];
    } else {
        for (int i = t; i < len; i += 256) {
            int2 e = ebuf[s0 + i];
            int slot = atomicAdd(&cnt[e.y], 1);
            csr_src[slot] = e.x;
        }
    }
}

// ------- GEMM: C[N][128](fp16) = A[N][K] @ W[K][128], fused als/ald -------

#define BM 32
#define BKK 32

__global__ __launch_bounds__(256) void gemm128_kernel(const float* __restrict__ A,
                                                      const float* __restrict__ W,
                                                      const float* __restrict__ avs,
                                                      const float* __restrict__ avd,
                                                      __half* __restrict__ C,
                                                      float* __restrict__ als,
                                                      float* __restrict__ ald,
                                                      int N, int K) {
    __shared__ float xs[BM][BKK + 1];
    __shared__ float ws[BKK][128];
    __shared__ float red_s[BM][9];
    __shared__ float red_d[BM][9];
    int tid = threadIdx.x;
    int r  = tid & 31;
    int cg = tid >> 5;
    int row0 = blockIdx.x * BM;

    float acc[16];
#pragma unroll
    for (int j = 0; j < 16; ++j) acc[j] = 0.f;

    for (int kk = 0; kk < K; kk += BKK) {
        {
            int lr = tid >> 3, lc = (tid & 7) * 4;
            int gr = row0 + lr;
            float4 v = make_float4(0.f, 0.f, 0.f, 0.f);
            if (gr < N) v = *reinterpret_cast<const float4*>(A + (size_t)gr * K + kk + lc);
            xs[lr][lc + 0] = v.x; xs[lr][lc + 1] = v.y;
            xs[lr][lc + 2] = v.z; xs[lr][lc + 3] = v.w;
        }
        {
            int wr = tid >> 3, wc = (tid & 7) * 16;
            const float4* src = reinterpret_cast<const float4*>(W + (size_t)(kk + wr) * 128 + wc);
            float4* dst = reinterpret_cast<float4*>(&ws[wr][wc]);
#pragma unroll
            for (int i = 0; i < 4; ++i) dst[i] = src[i];
        }
        __syncthreads();
#pragma unroll 8
        for (int k = 0; k < BKK; ++k) {
            float xv = xs[r][k];
            const float4* wrow = reinterpret_cast<const float4*>(&ws[k][cg * 16]);
#pragma unroll
            for (int q = 0; q < 4; ++q) {
                float4 wv = wrow[q];
                acc[q * 4 + 0] += xv * wv.x;
                acc[q * 4 + 1] += xv * wv.y;
                acc[q * 4 + 2] += xv * wv.z;
                acc[q * 4 + 3] += xv * wv.w;
            }
        }
        __syncthreads();
    }
    int gr = row0 + r;
    if (gr < N) {
        __half2* outp = reinterpret_cast<__half2*>(C + (size_t)gr * 128 + cg * 16);
#pragma unroll
        for (int q = 0; q < 8; ++q)
            outp[q] = __float22half2_rn(make_float2(acc[q * 2], acc[q * 2 + 1]));
    }
    // als/ald from fp32 accumulators (no quantization on the logit path)
    {
        float ps = 0.f, pd = 0.f;
#pragma unroll
        for (int q = 0; q < 16; ++q) {
            float a = acc[q];
            ps += a * avs[cg * 16 + q];
            pd += a * avd[cg * 16 + q];
        }
        red_s[r][cg] = ps;
        red_d[r][cg] = pd;
        __syncthreads();
        if (gr < N) {
            if (cg < 4) {
                als[(size_t)gr * 4 + cg] = red_s[r][2 * cg] + red_s[r][2 * cg + 1];
            } else {
                int hd = cg - 4;
                ald[(size_t)gr * 4 + hd] = red_d[r][2 * hd] + red_d[r][2 * hd + 1];
            }
        }
    }
}

// ---------------- wave-per-node aggregation (layers 0-2), fp16 h ----------------

__device__ __forceinline__ float lrelu(float x) { return x > 0.f ? x : NEG_SLOPE * x; }

__global__ __launch_bounds__(256) void agg_kernel(const __half* __restrict__ h,
                                                  const float* __restrict__ als4,
                                                  const float* __restrict__ ald4,
                                                  const int* __restrict__ row_start,
                                                  const int* __restrict__ csr_src,
                                                  const float* __restrict__ bias,
                                                  float* __restrict__ xout,
                                                  int N, int applyElu) {
    int v = (int)((blockIdx.x * blockDim.x + threadIdx.x) >> 6);
    int lane = threadIdx.x & 63;
    if (v >= N) return;
    int base = row_start[v], end = row_start[v + 1];

    int half_ = lane >> 5;
    int dim4 = (lane & 31) * 4;
    int hd2  = (lane & 31) >> 3;

    float aldh = ald4[(size_t)v * 4 + hd2];
    float alsh = als4[(size_t)v * 4 + hd2];
    float em = lrelu(alsh + aldh);
    const __half* hdim = h + dim4;
    const float* alsb = als4 + hd2;

    float4 acc  = make_float4(0.f, 0.f, 0.f, 0.f);
    float4 acc2 = make_float4(0.f, 0.f, 0.f, 0.f);
    float ssum = 0.f, ssum2 = 0.f;

    int j = base + half_;
    for (; j + 6 < end; j += 8) {
        int s0 = csr_src[j + 0];
        int s1 = csr_src[j + 2];
        int s2 = csr_src[j + 4];
        int s3 = csr_src[j + 6];
        float a0 = alsb[(size_t)s0 * 4];
        float a1 = alsb[(size_t)s1 * 4];
        float a2 = alsb[(size_t)s2 * 4];
        float a3 = alsb[(size_t)s3 * 4];
        uint2 r0 = *reinterpret_cast<const uint2*>(hdim + (size_t)s0 * 128);
        uint2 r1 = *reinterpret_cast<const uint2*>(hdim + (size_t)s1 * 128);
        uint2 r2 = *reinterpret_cast<const uint2*>(hdim + (size_t)s2 * 128);
        uint2 r3 = *reinterpret_cast<const uint2*>(hdim + (size_t)s3 * 128);
        float e0 = __expf(lrelu(a0 + aldh) - em);
        float e1 = __expf(lrelu(a1 + aldh) - em);
        float e2 = __expf(lrelu(a2 + aldh) - em);
        float e3 = __expf(lrelu(a3 + aldh) - em);
        ssum  += e0 + e2;
        ssum2 += e1 + e3;
        float2 f0a = __half22float2(*reinterpret_cast<__half2*>(&r0.x));
        float2 f0b = __half22float2(*reinterpret_cast<__half2*>(&r0.y));
        float2 f1a = __half22float2(*reinterpret_cast<__half2*>(&r1.x));
        float2 f1b = __half22float2(*reinterpret_cast<__half2*>(&r1.y));
        float2 f2a = __half22float2(*reinterpret_cast<__half2*>(&r2.x));
        float2 f2b = __half22float2(*reinterpret_cast<__half2*>(&r2.y));
        float2 f3a = __half22float2(*reinterpret_cast<__half2*>(&r3.x));
        float2 f3b = __half22float2(*reinterpret_cast<__half2*>(&r3.y));
        acc.x  += e0 * f0a.x; acc.y  += e0 * f0a.y; acc.z  += e0 * f0b.x; acc.w  += e0 * f0b.y;
        acc2.x += e1 * f1a.x; acc2.y += e1 * f1a.y; acc2.z += e1 * f1b.x; acc2.w += e1 * f1b.y;
        acc.x  += e2 * f2a.x; acc.y  += e2 * f2a.y; acc.z  += e2 * f2b.x; acc.w  += e2 * f2b.y;
        acc2.x += e3 * f3a.x; acc2.y += e3 * f3a.y; acc2.z += e3 * f3b.x; acc2.w += e3 * f3b.y;
    }
    for (; j < end; j += 2) {
        int s0 = csr_src[j];
        float a0 = alsb[(size_t)s0 * 4];
        uint2 r0 = *reinterpret_cast<const uint2*>(hdim + (size_t)s0 * 128);
        float e0 = __expf(lrelu(a0 + aldh) - em);
        ssum += e0;
        float2 f0a = __half22float2(*reinterpret_cast<__half2*>(&r0.x));
        float2 f0b = __half22float2(*reinterpret_cast<__half2*>(&r0.y));
        acc.x += e0 * f0a.x; acc.y += e0 * f0a.y; acc.z += e0 * f0b.x; acc.w += e0 * f0b.y;
    }
    acc.x += acc2.x; acc.y += acc2.y; acc.z += acc2.z; acc.w += acc2.w;
    ssum += ssum2;
    acc.x += __shfl_xor(acc.x, 32);
    acc.y += __shfl_xor(acc.y, 32);
    acc.z += __shfl_xor(acc.z, 32);
    acc.w += __shfl_xor(acc.w, 32);
    ssum  += __shfl_xor(ssum, 32);

    if (lane < 32) {
        float inv = 1.0f / (ssum + 1e-16f);
        float4 bv = *reinterpret_cast<const float4*>(bias + dim4);
        float4 o;
        o.x = acc.x * inv + bv.x;
        o.y = acc.y * inv + bv.y;
        o.z = acc.z * inv + bv.z;
        o.w = acc.w * inv + bv.w;
        if (applyElu) {
            o.x = o.x > 0.f ? o.x : expm1f(o.x);
            o.y = o.y > 0.f ? o.y : expm1f(o.y);
            o.z = o.z > 0.f ? o.z : expm1f(o.z);
            o.w = o.w > 0.f ? o.w : expm1f(o.w);
        }
        *reinterpret_cast<float4*>(xout + (size_t)v * 128 + dim4) = o;
    }
}

// ---------------- layer 3: GEMM [N,128]x[128,6] with fused al ----------------

__global__ void gemm3_kernel(const float* __restrict__ x, const float* __restrict__ W,
                             const float* __restrict__ as3, const float* __restrict__ ad3,
                             float* __restrict__ h3, float* __restrict__ als3,
                             float* __restrict__ ald3, int N) {
    int n = blockIdx.x * blockDim.x + threadIdx.x;
    if (n >= N) return;
    float acc[6] = {0.f, 0.f, 0.f, 0.f, 0.f, 0.f};
    const float4* xp = reinterpret_cast<const float4*>(x + (size_t)n * 128);
#pragma unroll 4
    for (int k4 = 0; k4 < 32; ++k4) {
        float4 xv = xp[k4];
        const float* w0 = W + (size_t)(k4 * 4) * 6;
#pragma unroll
        for (int j = 0; j < 6; ++j)
            acc[j] += xv.x * w0[j] + xv.y * w0[6 + j] + xv.z * w0[12 + j] + xv.w * w0[18 + j];
    }
    float s = 0.f, d = 0.f;
#pragma unroll
    for (int j = 0; j < 6; ++j) {
        s += acc[j] * as3[j];
        d += acc[j] * ad3[j];
        h3[(size_t)n * 6 + j] = acc[j];
    }
    als3[n] = s;
    ald3[n] = d;
}

__global__ void agg3_kernel(const float* __restrict__ h3, const float* __restrict__ als3,
                            const float* __restrict__ ald3, const int* __restrict__ row_start,
                            const int* __restrict__ csr_src, const float* __restrict__ b3,
                            float* __restrict__ out, int N) {
    int v = blockIdx.x * blockDim.x + threadIdx.x;
    if (v >= N) return;
    int base = row_start[v], end = row_start[v + 1];
    float aldv = ald3[v];
    float em = lrelu(als3[v] + aldv);
    float ssum = 0.f;
    float acc[6] = {0.f, 0.f, 0.f, 0.f, 0.f, 0.f};
    float acc2[6] = {0.f, 0.f, 0.f, 0.f, 0.f, 0.f};
    int j = base;
    for (; j + 1 < end; j += 2) {
        int sa = csr_src[j], sb = csr_src[j + 1];
        float ea = __expf(lrelu(als3[sa] + aldv) - em);
        float eb = __expf(lrelu(als3[sb] + aldv) - em);
        ssum += ea + eb;
        const float* ha = h3 + (size_t)sa * 6;
        const float* hb = h3 + (size_t)sb * 6;
#pragma unroll
        for (int q = 0; q < 6; ++q) acc[q] += ea * ha[q];
#pragma unroll
        for (int q = 0; q < 6; ++q) acc2[q] += eb * hb[q];
    }
    if (j < end) {
        int sa = csr_src[j];
        float ea = __expf(lrelu(als3[sa] + aldv) - em);
        ssum += ea;
        const float* ha = h3 + (size_t)sa * 6;
#pragma unroll
        for (int q = 0; q < 6; ++q) acc[q] += ea * ha[q];
    }
    float inv = 1.f / (ssum + 1e-16f);
#pragma unroll
    for (int q = 0; q < 6; ++q) out[(size_t)v * 6 + q] = (acc[q] + acc2[q]) * inv + b3[q];
}

// ---------------- launch ----------------

extern "C" void kernel_launch(void* const* d_in, const int* in_sizes, int n_in,
                              void* d_out, int out_size, void* d_ws, size_t ws_size,
                              hipStream_t stream) {
    const float* x    = (const float*)d_in[0];
    const int*   ei   = (const int*)d_in[1];
    const float* W0   = (const float*)d_in[3];
    const float* as0  = (const float*)d_in[4];
    const float* ad0  = (const float*)d_in[5];
    const float* b0   = (const float*)d_in[6];
    const float* W1   = (const float*)d_in[7];
    const float* as1  = (const float*)d_in[8];
    const float* ad1  = (const float*)d_in[9];
    const float* b1   = (const float*)d_in[10];
    const float* W2   = (const float*)d_in[11];
    const float* as2  = (const float*)d_in[12];
    const float* ad2  = (const float*)d_in[13];
    const float* b2   = (const float*)d_in[14];
    const float* W3   = (const float*)d_in[15];
    const float* as3  = (const float*)d_in[16];
    const float* ad3  = (const float*)d_in[17];
    const float* b3   = (const float*)d_in[18];
    float* out = (float*)d_out;

    int N = in_sizes[0] / IN_CH;
    int E = in_sizes[1] / 2;
    int EN = E + N;
    int NB = (N + 255) >> 8;            // buckets of 256 dsts (assumes NB <= 512)
    int epb = (EN + PBLK - 1) / PBLK;   // edges per partition block

    char* p = (char*)d_ws;
    auto alloc = [&](size_t bytes) {
        char* q = p;
        p += (bytes + 255) & ~(size_t)255;
        return q;
    };
    __half* hbuf = (__half*)alloc((size_t)N * 128 * 2);
    float* xA   = (float*)alloc((size_t)N * 128 * 4);
    float* xB   = (float*)alloc((size_t)N * 128 * 4);
    float* als  = (float*)alloc((size_t)N * 4 * 4);
    float* ald  = (float*)alloc((size_t)N * 4 * 4);
    float* h3   = (float*)alloc((size_t)N * 6 * 4);
    float* als3 = (float*)alloc((size_t)N * 4);
    float* ald3 = (float*)alloc((size_t)N * 4);
    int* row_start = (int*)alloc((size_t)(N + 1) * 4);
    int* csr_src   = (int*)alloc((size_t)EN * 4);
    int2* ebuf     = (int2*)alloc((size_t)EN * 8);
    int* counts    = (int*)alloc((size_t)NB * PBLK * 4);
    int* btot      = (int*)alloc((size_t)NB * 4);
    int* bstart    = (int*)alloc((size_t)(NB + 1) * 4);
    (void)ws_size; (void)n_in; (void)out_size;

    // ---- CSR build (no global atomics) ----
    part_count<<<PBLK, 256, 0, stream>>>(ei, E, EN, NB, epb, counts);
    bucket_tot<<<NB, 256, 0, stream>>>(counts, btot);
    bucket_scan<<<1, 256, 0, stream>>>(btot, NB, EN, bstart);
    bucket_base<<<NB, 256, 0, stream>>>(counts, bstart);
    part_scatter<<<PBLK, 256, 0, stream>>>(ei, E, EN, NB, epb, counts, ebuf);
    bucket_csr<<<NB, 256, 0, stream>>>(ebuf, bstart, NB, N, EN, row_start, csr_src);

    int gemm_grid = (N + BM - 1) / BM;
    int agg_grid  = (N + 3) / 4;
    int n_grid    = (N + 255) / 256;

    // ---- layer 0 ----
    gemm128_kernel<<<gemm_grid, 256, 0, stream>>>(x, W0, as0, ad0, hbuf, als, ald, N, 64);
    agg_kernel<<<agg_grid, 256, 0, stream>>>(hbuf, als, ald, row_start, csr_src, b0, xA, N, 1);

    // ---- layer 1 ----
    gemm128_kernel<<<gemm_grid, 256, 0, stream>>>(xA, W1, as1, ad1, hbuf, als, ald, N, 128);
    agg_kernel<<<agg_grid, 256, 0, stream>>>(hbuf, als, ald, row_start, csr_src, b1, xB, N, 1);

    // ---- layer 2 ----
    gemm128_kernel<<<gemm_grid, 256, 0, stream>>>(xB, W2, as2, ad2, hbuf, als, ald, N, 128);
    agg_kernel<<<agg_grid, 256, 0, stream>>>(hbuf, als, ald, row_start, csr_src, b2, xA, N, 1);

    // ---- layer 3 ----
    gemm3_kernel<<<n_grid, 256, 0, stream>>>(xA, W3, as3, ad3, h3, als3, ald3, N);
    agg3_kernel<<<n_grid, 256, 0, stream>>>(h3, als3, ald3, row_start, csr_src, b3, out, N);
}

// Round 10
// 458.220 us; speedup vs baseline: 2.1433x; 1.1381x over previous
//
#include <hip/hip_runtime.h>
#include <hip/hip_bf16.h>
#include <hip/hip_fp16.h>

#define IN_CH 64
#define HID 32
#define HEADS 4
#define OUT_CH 6
#define NEG_SLOPE 0.2f

// ============== CSR build: bucket-partitioned, LDS-atomic only ==============

#define PBLK 256
#define CAP 6144

__global__ __launch_bounds__(256) void part_count(const int* __restrict__ ei, int E, int EN,
                                                  int NB, int epb, int* __restrict__ counts) {
    __shared__ int cnt[512];
    int b = blockIdx.x, t = threadIdx.x;
    for (int i = t; i < NB; i += 256) cnt[i] = 0;
    __syncthreads();
    int e0 = b * epb;
    int e1 = min(e0 + epb, EN);
    for (int e = e0 + t; e < e1; e += 256) {
        int d = (e < E) ? ei[E + e] : (e - E);
        atomicAdd(&cnt[d >> 8], 1);
    }
    __syncthreads();
    for (int i = t; i < NB; i += 256) counts[(size_t)i * PBLK + b] = cnt[i];
}

__global__ __launch_bounds__(256) void bucket_tot(const int* __restrict__ counts,
                                                  int* __restrict__ btot) {
    __shared__ int red[256];
    int k = blockIdx.x, t = threadIdx.x;
    red[t] = counts[(size_t)k * PBLK + t];
    __syncthreads();
    for (int off = 128; off; off >>= 1) {
        if (t < off) red[t] += red[t + off];
        __syncthreads();
    }
    if (t == 0) btot[k] = red[0];
}

__global__ __launch_bounds__(256) void bucket_scan(const int* __restrict__ btot, int NB, int EN,
                                                   int* __restrict__ bstart) {
    __shared__ int tmp[256];
    int t = threadIdx.x;
    int chunk = (NB + 255) >> 8;
    int s0 = t * chunk, s1 = min(s0 + chunk, NB);
    int sum = 0;
    for (int i = s0; i < s1; ++i) sum += btot[i];
    tmp[t] = sum;
    __syncthreads();
    for (int off = 1; off < 256; off <<= 1) {
        int v = (t >= off) ? tmp[t - off] : 0;
        __syncthreads();
        tmp[t] += v;
        __syncthreads();
    }
    int run = (t == 0) ? 0 : tmp[t - 1];
    for (int i = s0; i < s1; ++i) {
        int c = btot[i];
        bstart[i] = run;
        run += c;
    }
    if (t == 255) bstart[NB] = EN;
}

__global__ __launch_bounds__(256) void bucket_base(int* __restrict__ counts,
                                                   const int* __restrict__ bstart) {
    __shared__ int sc[256];
    int k = blockIdx.x, t = threadIdx.x;
    int v = counts[(size_t)k * PBLK + t];
    sc[t] = v;
    __syncthreads();
    for (int off = 1; off < 256; off <<= 1) {
        int u = (t >= off) ? sc[t - off] : 0;
        __syncthreads();
        sc[t] += u;
        __syncthreads();
    }
    counts[(size_t)k * PBLK + t] = bstart[k] + sc[t] - v;
}

__global__ __launch_bounds__(256) void part_scatter(const int* __restrict__ ei, int E, int EN,
                                                    int NB, int epb,
                                                    const int* __restrict__ base,
                                                    int2* __restrict__ ebuf) {
    __shared__ int cur[512];
    int b = blockIdx.x, t = threadIdx.x;
    for (int i = t; i < NB; i += 256) cur[i] = base[(size_t)i * PBLK + b];
    __syncthreads();
    int e0 = b * epb;
    int e1 = min(e0 + epb, EN);
    for (int e = e0 + t; e < e1; e += 256) {
        int s, d;
        if (e < E) { s = ei[e]; d = ei[E + e]; }
        else       { s = e - E; d = s; }
        int slot = atomicAdd(&cur[d >> 8], 1);
        ebuf[slot] = make_int2(s, d & 255);
    }
}

__global__ __launch_bounds__(256) void bucket_csr(const int2* __restrict__ ebuf,
                                                  const int* __restrict__ bstart,
                                                  int NB, int N, int EN,
                                                  int* __restrict__ row_start,
                                                  int* __restrict__ csr_src) {
    __shared__ int cnt[256];
    __shared__ int sc[256];
    __shared__ int stage[CAP];
    int k = blockIdx.x, t = threadIdx.x;
    int s0 = bstart[k], s1 = bstart[k + 1];
    int len = s1 - s0;
    cnt[t] = 0;
    __syncthreads();
    for (int i = t; i < len; i += 256) atomicAdd(&cnt[ebuf[s0 + i].y], 1);
    __syncthreads();
    int v = cnt[t];
    sc[t] = v;
    __syncthreads();
    for (int off = 1; off < 256; off <<= 1) {
        int u = (t >= off) ? sc[t - off] : 0;
        __syncthreads();
        sc[t] += u;
        __syncthreads();
    }
    int excl = sc[t] - v;
    int g = (k << 8) + t;
    if (g < N) row_start[g] = s0 + excl;
    if (k == NB - 1 && t == 0) row_start[N] = EN;
    bool fits = (len <= CAP);
    cnt[t] = fits ? excl : s0 + excl;
    __syncthreads();
    if (fits) {
        for (int i = t; i < len; i += 256) {
            int2 e = ebuf[s0 + i];
            int slot = atomicAdd(&cnt[e.y], 1);
            stage[slot] = e.x;
        }
        __syncthreads();
        for (int i = t; i < len; i += 256) csr_src[s0 + i] = stage[i];
    } else {
        for (int i = t; i < len; i += 256) {
            int2 e = ebuf[s0 + i];
            int slot = atomicAdd(&cnt[e.y], 1);
            csr_src[slot] = e.x;
        }
    }
}

// ------- GEMM: C[N][128](fp16) = A[N][K] @ W[K][128], register-tiled -------
// BM=64, 256 threads = 8 row-groups x 32 col-threads, 8x4 outputs/thread.
// A staged transposed xsT[k][row] (stride 68: 16B-aligned, 2-way-max banks);
// W staged ws[k][col] via flat consecutive-float4 writes (conflict-free).
// Inner loop per k: 2 broadcast b128 (A) + 1 coalesced b128 (W) -> 32 FMAs.

#define GBM 64
#define GBK 32
#define XST 68

__global__ __launch_bounds__(256) void gemm128_kernel(const float* __restrict__ A,
                                                      const float* __restrict__ W,
                                                      const float* __restrict__ avs,
                                                      const float* __restrict__ avd,
                                                      __half* __restrict__ C,
                                                      float* __restrict__ als,
                                                      float* __restrict__ ald,
                                                      int N, int K) {
    __shared__ float xsT[GBK][XST];     // [k][row], 68-float stride
    __shared__ float ws[GBK][128];      // [k][col]
    int tid = threadIdx.x;
    int rt = tid >> 5;                  // 0..7 row group
    int ct = tid & 31;                  // 0..31 col thread
    int row0 = blockIdx.x * GBM;

    float acc[8][4];
#pragma unroll
    for (int i = 0; i < 8; ++i)
#pragma unroll
        for (int j = 0; j < 4; ++j) acc[i][j] = 0.f;

    int arow = tid & 63;                // A-stage: row
    int acg  = (tid >> 6) * 8;          // A-stage: 8-col group
    int garow = row0 + arow;

    for (int kk = 0; kk < K; kk += GBK) {
        {   // stage A transposed: 8 scalar writes, banks (4i+arow)%32 -> 2-way max
            float4 a0 = make_float4(0.f, 0.f, 0.f, 0.f);
            float4 a1 = make_float4(0.f, 0.f, 0.f, 0.f);
            if (garow < N) {
                const float4* ap = reinterpret_cast<const float4*>(A + (size_t)garow * K + kk + acg);
                a0 = ap[0]; a1 = ap[1];
            }
            xsT[acg + 0][arow] = a0.x; xsT[acg + 1][arow] = a0.y;
            xsT[acg + 2][arow] = a0.z; xsT[acg + 3][arow] = a0.w;
            xsT[acg + 4][arow] = a1.x; xsT[acg + 5][arow] = a1.y;
            xsT[acg + 6][arow] = a1.z; xsT[acg + 7][arow] = a1.w;
        }
        {   // stage W: flat float4 index p = tid + 256c -> ws[p>>5][(p&31)*4]
            float4* wflat = reinterpret_cast<float4*>(&ws[0][0]);
            const float4* wsrc = reinterpret_cast<const float4*>(W + (size_t)kk * 128);
#pragma unroll
            for (int c = 0; c < 4; ++c) {
                int p = tid + 256 * c;
                wflat[p] = wsrc[p];
            }
        }
        __syncthreads();
#pragma unroll 4
        for (int k = 0; k < GBK; ++k) {
            float4 av0 = *reinterpret_cast<const float4*>(&xsT[k][rt * 8]);
            float4 av1 = *reinterpret_cast<const float4*>(&xsT[k][rt * 8 + 4]);
            float4 wv  = *reinterpret_cast<const float4*>(&ws[k][ct * 4]);
            acc[0][0] += av0.x * wv.x; acc[0][1] += av0.x * wv.y; acc[0][2] += av0.x * wv.z; acc[0][3] += av0.x * wv.w;
            acc[1][0] += av0.y * wv.x; acc[1][1] += av0.y * wv.y; acc[1][2] += av0.y * wv.z; acc[1][3] += av0.y * wv.w;
            acc[2][0] += av0.z * wv.x; acc[2][1] += av0.z * wv.y; acc[2][2] += av0.z * wv.z; acc[2][3] += av0.z * wv.w;
            acc[3][0] += av0.w * wv.x; acc[3][1] += av0.w * wv.y; acc[3][2] += av0.w * wv.z; acc[3][3] += av0.w * wv.w;
            acc[4][0] += av1.x * wv.x; acc[4][1] += av1.x * wv.y; acc[4][2] += av1.x * wv.z; acc[4][3] += av1.x * wv.w;
            acc[5][0] += av1.y * wv.x; acc[5][1] += av1.y * wv.y; acc[5][2] += av1.y * wv.z; acc[5][3] += av1.y * wv.w;
            acc[6][0] += av1.z * wv.x; acc[6][1] += av1.z * wv.y; acc[6][2] += av1.z * wv.z; acc[6][3] += av1.z * wv.w;
            acc[7][0] += av1.w * wv.x; acc[7][1] += av1.w * wv.y; acc[7][2] += av1.w * wv.z; acc[7][3] += av1.w * wv.w;
        }
        __syncthreads();
    }

    // C store: rows rt*8..+8, cols ct*4..+4 (fp16)
#pragma unroll
    for (int i = 0; i < 8; ++i) {
        int gr = row0 + rt * 8 + i;
        if (gr < N) {
            __half2* outp = reinterpret_cast<__half2*>(C + (size_t)gr * 128 + ct * 4);
            outp[0] = __float22half2_rn(make_float2(acc[i][0], acc[i][1]));
            outp[1] = __float22half2_rn(make_float2(acc[i][2], acc[i][3]));
        }
    }
    // als/ald: reduce over the 8 col-threads of each head (lane bits 0-2)
    float avs_c[4], avd_c[4];
#pragma unroll
    for (int j = 0; j < 4; ++j) {
        avs_c[j] = avs[ct * 4 + j];
        avd_c[j] = avd[ct * 4 + j];
    }
#pragma unroll
    for (int i = 0; i < 8; ++i) {
        float ps = acc[i][0] * avs_c[0] + acc[i][1] * avs_c[1] + acc[i][2] * avs_c[2] + acc[i][3] * avs_c[3];
        float pd = acc[i][0] * avd_c[0] + acc[i][1] * avd_c[1] + acc[i][2] * avd_c[2] + acc[i][3] * avd_c[3];
        ps += __shfl_xor(ps, 1); pd += __shfl_xor(pd, 1);
        ps += __shfl_xor(ps, 2); pd += __shfl_xor(pd, 2);
        ps += __shfl_xor(ps, 4); pd += __shfl_xor(pd, 4);
        if ((ct & 7) == 0) {
            int gr = row0 + rt * 8 + i;
            int hd = ct >> 3;
            if (gr < N) {
                als[(size_t)gr * 4 + hd] = ps;
                ald[(size_t)gr * 4 + hd] = pd;
            }
        }
    }
}

// ---------------- wave-per-node aggregation (layers 0-2), fp16 h ----------------

__device__ __forceinline__ float lrelu(float x) { return x > 0.f ? x : NEG_SLOPE * x; }

__global__ __launch_bounds__(256) void agg_kernel(const __half* __restrict__ h,
                                                  const float* __restrict__ als4,
                                                  const float* __restrict__ ald4,
                                                  const int* __restrict__ row_start,
                                                  const int* __restrict__ csr_src,
                                                  const float* __restrict__ bias,
                                                  float* __restrict__ xout,
                                                  int N, int applyElu) {
    int v = (int)((blockIdx.x * blockDim.x + threadIdx.x) >> 6);
    int lane = threadIdx.x & 63;
    if (v >= N) return;
    int base = row_start[v], end = row_start[v + 1];

    int half_ = lane >> 5;
    int dim4 = (lane & 31) * 4;
    int hd2  = (lane & 31) >> 3;

    float aldh = ald4[(size_t)v * 4 + hd2];
    float alsh = als4[(size_t)v * 4 + hd2];
    float em = lrelu(alsh + aldh);
    const __half* hdim = h + dim4;
    const float* alsb = als4 + hd2;

    float4 acc  = make_float4(0.f, 0.f, 0.f, 0.f);
    float4 acc2 = make_float4(0.f, 0.f, 0.f, 0.f);
    float ssum = 0.f, ssum2 = 0.f;

    int j = base + half_;
    for (; j + 6 < end; j += 8) {
        int s0 = csr_src[j + 0];
        int s1 = csr_src[j + 2];
        int s2 = csr_src[j + 4];
        int s3 = csr_src[j + 6];
        float a0 = alsb[(size_t)s0 * 4];
        float a1 = alsb[(size_t)s1 * 4];
        float a2 = alsb[(size_t)s2 * 4];
        float a3 = alsb[(size_t)s3 * 4];
        uint2 r0 = *reinterpret_cast<const uint2*>(hdim + (size_t)s0 * 128);
        uint2 r1 = *reinterpret_cast<const uint2*>(hdim + (size_t)s1 * 128);
        uint2 r2 = *reinterpret_cast<const uint2*>(hdim + (size_t)s2 * 128);
        uint2 r3 = *reinterpret_cast<const uint2*>(hdim + (size_t)s3 * 128);
        float e0 = __expf(lrelu(a0 + aldh) - em);
        float e1 = __expf(lrelu(a1 + aldh) - em);
        float e2 = __expf(lrelu(a2 + aldh) - em);
        float e3 = __expf(lrelu(a3 + aldh) - em);
        ssum  += e0 + e2;
        ssum2 += e1 + e3;
        float2 f0a = __half22float2(*reinterpret_cast<__half2*>(&r0.x));
        float2 f0b = __half22float2(*reinterpret_cast<__half2*>(&r0.y));
        float2 f1a = __half22float2(*reinterpret_cast<__half2*>(&r1.x));
        float2 f1b = __half22float2(*reinterpret_cast<__half2*>(&r1.y));
        float2 f2a = __half22float2(*reinterpret_cast<__half2*>(&r2.x));
        float2 f2b = __half22float2(*reinterpret_cast<__half2*>(&r2.y));
        float2 f3a = __half22float2(*reinterpret_cast<__half2*>(&r3.x));
        float2 f3b = __half22float2(*reinterpret_cast<__half2*>(&r3.y));
        acc.x  += e0 * f0a.x; acc.y  += e0 * f0a.y; acc.z  += e0 * f0b.x; acc.w  += e0 * f0b.y;
        acc2.x += e1 * f1a.x; acc2.y += e1 * f1a.y; acc2.z += e1 * f1b.x; acc2.w += e1 * f1b.y;
        acc.x  += e2 * f2a.x; acc.y  += e2 * f2a.y; acc.z  += e2 * f2b.x; acc.w  += e2 * f2b.y;
        acc2.x += e3 * f3a.x; acc2.y += e3 * f3a.y; acc2.z += e3 * f3b.x; acc2.w += e3 * f3b.y;
    }
    for (; j < end; j += 2) {
        int s0 = csr_src[j];
        float a0 = alsb[(size_t)s0 * 4];
        uint2 r0 = *reinterpret_cast<const uint2*>(hdim + (size_t)s0 * 128);
        float e0 = __expf(lrelu(a0 + aldh) - em);
        ssum += e0;
        float2 f0a = __half22float2(*reinterpret_cast<__half2*>(&r0.x));
        float2 f0b = __half22float2(*reinterpret_cast<__half2*>(&r0.y));
        acc.x += e0 * f0a.x; acc.y += e0 * f0a.y; acc.z += e0 * f0b.x; acc.w += e0 * f0b.y;
    }
    acc.x += acc2.x; acc.y += acc2.y; acc.z += acc2.z; acc.w += acc2.w;
    ssum += ssum2;
    acc.x += __shfl_xor(acc.x, 32);
    acc.y += __shfl_xor(acc.y, 32);
    acc.z += __shfl_xor(acc.z, 32);
    acc.w += __shfl_xor(acc.w, 32);
    ssum  += __shfl_xor(ssum, 32);

    if (lane < 32) {
        float inv = 1.0f / (ssum + 1e-16f);
        float4 bv = *reinterpret_cast<const float4*>(bias + dim4);
        float4 o;
        o.x = acc.x * inv + bv.x;
        o.y = acc.y * inv + bv.y;
        o.z = acc.z * inv + bv.z;
        o.w = acc.w * inv + bv.w;
        if (applyElu) {
            o.x = o.x > 0.f ? o.x : expm1f(o.x);
            o.y = o.y > 0.f ? o.y : expm1f(o.y);
            o.z = o.z > 0.f ? o.z : expm1f(o.z);
            o.w = o.w > 0.f ? o.w : expm1f(o.w);
        }
        *reinterpret_cast<float4*>(xout + (size_t)v * 128 + dim4) = o;
    }
}

// ---------------- layer 3: GEMM [N,128]x[128,6] with fused al ----------------

__global__ void gemm3_kernel(const float* __restrict__ x, const float* __restrict__ W,
                             const float* __restrict__ as3, const float* __restrict__ ad3,
                             float* __restrict__ h3, float* __restrict__ als3,
                             float* __restrict__ ald3, int N) {
    int n = blockIdx.x * blockDim.x + threadIdx.x;
    if (n >= N) return;
    float acc[6] = {0.f, 0.f, 0.f, 0.f, 0.f, 0.f};
    const float4* xp = reinterpret_cast<const float4*>(x + (size_t)n * 128);
#pragma unroll 4
    for (int k4 = 0; k4 < 32; ++k4) {
        float4 xv = xp[k4];
        const float* w0 = W + (size_t)(k4 * 4) * 6;
#pragma unroll
        for (int j = 0; j < 6; ++j)
            acc[j] += xv.x * w0[j] + xv.y * w0[6 + j] + xv.z * w0[12 + j] + xv.w * w0[18 + j];
    }
    float s = 0.f, d = 0.f;
#pragma unroll
    for (int j = 0; j < 6; ++j) {
        s += acc[j] * as3[j];
        d += acc[j] * ad3[j];
        h3[(size_t)n * 6 + j] = acc[j];
    }
    als3[n] = s;
    ald3[n] = d;
}

__global__ void agg3_kernel(const float* __restrict__ h3, const float* __restrict__ als3,
                            const float* __restrict__ ald3, const int* __restrict__ row_start,
                            const int* __restrict__ csr_src, const float* __restrict__ b3,
                            float* __restrict__ out, int N) {
    int v = blockIdx.x * blockDim.x + threadIdx.x;
    if (v >= N) return;
    int base = row_start[v], end = row_start[v + 1];
    float aldv = ald3[v];
    float em = lrelu(als3[v] + aldv);
    float ssum = 0.f;
    float acc[6] = {0.f, 0.f, 0.f, 0.f, 0.f, 0.f};
    float acc2[6] = {0.f, 0.f, 0.f, 0.f, 0.f, 0.f};
    int j = base;
    for (; j + 1 < end; j += 2) {
        int sa = csr_src[j], sb = csr_src[j + 1];
        float ea = __expf(lrelu(als3[sa] + aldv) - em);
        float eb = __expf(lrelu(als3[sb] + aldv) - em);
        ssum += ea + eb;
        const float* ha = h3 + (size_t)sa * 6;
        const float* hb = h3 + (size_t)sb * 6;
#pragma unroll
        for (int q = 0; q < 6; ++q) acc[q] += ea * ha[q];
#pragma unroll
        for (int q = 0; q < 6; ++q) acc2[q] += eb * hb[q];
    }
    if (j < end) {
        int sa = csr_src[j];
        float ea = __expf(lrelu(als3[sa] + aldv) - em);
        ssum += ea;
        const float* ha = h3 + (size_t)sa * 6;
#pragma unroll
        for (int q = 0; q < 6; ++q) acc[q] += ea * ha[q];
    }
    float inv = 1.f / (ssum + 1e-16f);
#pragma unroll
    for (int q = 0; q < 6; ++q) out[(size_t)v * 6 + q] = (acc[q] + acc2[q]) * inv + b3[q];
}

// ---------------- launch ----------------

extern "C" void kernel_launch(void* const* d_in, const int* in_sizes, int n_in,
                              void* d_out, int out_size, void* d_ws, size_t ws_size,
                              hipStream_t stream) {
    const float* x    = (const float*)d_in[0];
    const int*   ei   = (const int*)d_in[1];
    const float* W0   = (const float*)d_in[3];
    const float* as0  = (const float*)d_in[4];
    const float* ad0  = (const float*)d_in[5];
    const float* b0   = (const float*)d_in[6];
    const float* W1   = (const float*)d_in[7];
    const float* as1  = (const float*)d_in[8];
    const float* ad1  = (const float*)d_in[9];
    const float* b1   = (const float*)d_in[10];
    const float* W2   = (const float*)d_in[11];
    const float* as2  = (const float*)d_in[12];
    const float* ad2  = (const float*)d_in[13];
    const float* b2   = (const float*)d_in[14];
    const float* W3   = (const float*)d_in[15];
    const float* as3  = (const float*)d_in[16];
    const float* ad3  = (const float*)d_in[17];
    const float* b3   = (const float*)d_in[18];
    float* out = (float*)d_out;

    int N = in_sizes[0] / IN_CH;
    int E = in_sizes[1] / 2;
    int EN = E + N;
    int NB = (N + 255) >> 8;
    int epb = (EN + PBLK - 1) / PBLK;

    char* p = (char*)d_ws;
    auto alloc = [&](size_t bytes) {
        char* q = p;
        p += (bytes + 255) & ~(size_t)255;
        return q;
    };
    __half* hbuf = (__half*)alloc((size_t)N * 128 * 2);
    float* xA   = (float*)alloc((size_t)N * 128 * 4);
    float* xB   = (float*)alloc((size_t)N * 128 * 4);
    float* als  = (float*)alloc((size_t)N * 4 * 4);
    float* ald  = (float*)alloc((size_t)N * 4 * 4);
    float* h3   = (float*)alloc((size_t)N * 6 * 4);
    float* als3 = (float*)alloc((size_t)N * 4);
    float* ald3 = (float*)alloc((size_t)N * 4);
    int* row_start = (int*)alloc((size_t)(N + 1) * 4);
    int* csr_src   = (int*)alloc((size_t)EN * 4);
    int2* ebuf     = (int2*)alloc((size_t)EN * 8);
    int* counts    = (int*)alloc((size_t)NB * PBLK * 4);
    int* btot      = (int*)alloc((size_t)NB * 4);
    int* bstart    = (int*)alloc((size_t)(NB + 1) * 4);
    (void)ws_size; (void)n_in; (void)out_size;

    // ---- CSR build (no global atomics) ----
    part_count<<<PBLK, 256, 0, stream>>>(ei, E, EN, NB, epb, counts);
    bucket_tot<<<NB, 256, 0, stream>>>(counts, btot);
    bucket_scan<<<1, 256, 0, stream>>>(btot, NB, EN, bstart);
    bucket_base<<<NB, 256, 0, stream>>>(counts, bstart);
    part_scatter<<<PBLK, 256, 0, stream>>>(ei, E, EN, NB, epb, counts, ebuf);
    bucket_csr<<<NB, 256, 0, stream>>>(ebuf, bstart, NB, N, EN, row_start, csr_src);

    int gemm_grid = (N + GBM - 1) / GBM;
    int agg_grid  = (N + 3) / 4;
    int n_grid    = (N + 255) / 256;

    // ---- layer 0 ----
    gemm128_kernel<<<gemm_grid, 256, 0, stream>>>(x, W0, as0, ad0, hbuf, als, ald, N, 64);
    agg_kernel<<<agg_grid, 256, 0, stream>>>(hbuf, als, ald, row_start, csr_src, b0, xA, N, 1);

    // ---- layer 1 ----
    gemm128_kernel<<<gemm_grid, 256, 0, stream>>>(xA, W1, as1, ad1, hbuf, als, ald, N, 128);
    agg_kernel<<<agg_grid, 256, 0, stream>>>(hbuf, als, ald, row_start, csr_src, b1, xB, N, 1);

    // ---- layer 2 ----
    gemm128_kernel<<<gemm_grid, 256, 0, stream>>>(xB, W2, as2, ad2, hbuf, als, ald, N, 128);
    agg_kernel<<<agg_grid, 256, 0, stream>>>(hbuf, als, ald, row_start, csr_src, b2, xA, N, 1);

    // ---- layer 3 ----
    gemm3_kernel<<<n_grid, 256, 0, stream>>>(xA, W3, as3, ad3, h3, als3, ald3, N);
    agg3_kernel<<<n_grid, 256, 0, stream>>>(h3, als3, ald3, row_start, csr_src, b3, out, N);
}

// Round 11
// 445.773 us; speedup vs baseline: 2.2032x; 1.0279x over previous
//
#include <hip/hip_runtime.h>
#include <hip/hip_bf16.h>
#include <hip/hip_fp16.h>

#define IN_CH 64
#define HID 32
#define HEADS 4
#define OUT_CH 6
#define NEG_SLOPE 0.2f

typedef __attribute__((ext_vector_type(8))) _Float16 half8;
typedef __attribute__((ext_vector_type(4))) float f32x4;

// ============== CSR build: bucket-partitioned, LDS-atomic only ==============

#define PBLK 256
#define CAP 6144

__global__ __launch_bounds__(256) void part_count(const int* __restrict__ ei, int E, int EN,
                                                  int NB, int epb, int* __restrict__ counts) {
    __shared__ int cnt[512];
    int b = blockIdx.x, t = threadIdx.x;
    for (int i = t; i < NB; i += 256) cnt[i] = 0;
    __syncthreads();
    int e0 = b * epb;
    int e1 = min(e0 + epb, EN);
    for (int e = e0 + t; e < e1; e += 256) {
        int d = (e < E) ? ei[E + e] : (e - E);
        atomicAdd(&cnt[d >> 8], 1);
    }
    __syncthreads();
    for (int i = t; i < NB; i += 256) counts[(size_t)i * PBLK + b] = cnt[i];
}

__global__ __launch_bounds__(256) void bucket_tot(const int* __restrict__ counts,
                                                  int* __restrict__ btot) {
    __shared__ int red[256];
    int k = blockIdx.x, t = threadIdx.x;
    red[t] = counts[(size_t)k * PBLK + t];
    __syncthreads();
    for (int off = 128; off; off >>= 1) {
        if (t < off) red[t] += red[t + off];
        __syncthreads();
    }
    if (t == 0) btot[k] = red[0];
}

__global__ __launch_bounds__(256) void bucket_scan(const int* __restrict__ btot, int NB, int EN,
                                                   int* __restrict__ bstart) {
    __shared__ int tmp[256];
    int t = threadIdx.x;
    int chunk = (NB + 255) >> 8;
    int s0 = t * chunk, s1 = min(s0 + chunk, NB);
    int sum = 0;
    for (int i = s0; i < s1; ++i) sum += btot[i];
    tmp[t] = sum;
    __syncthreads();
    for (int off = 1; off < 256; off <<= 1) {
        int v = (t >= off) ? tmp[t - off] : 0;
        __syncthreads();
        tmp[t] += v;
        __syncthreads();
    }
    int run = (t == 0) ? 0 : tmp[t - 1];
    for (int i = s0; i < s1; ++i) {
        int c = btot[i];
        bstart[i] = run;
        run += c;
    }
    if (t == 255) bstart[NB] = EN;
}

__global__ __launch_bounds__(256) void bucket_base(int* __restrict__ counts,
                                                   const int* __restrict__ bstart) {
    __shared__ int sc[256];
    int k = blockIdx.x, t = threadIdx.x;
    int v = counts[(size_t)k * PBLK + t];
    sc[t] = v;
    __syncthreads();
    for (int off = 1; off < 256; off <<= 1) {
        int u = (t >= off) ? sc[t - off] : 0;
        __syncthreads();
        sc[t] += u;
        __syncthreads();
    }
    counts[(size_t)k * PBLK + t] = bstart[k] + sc[t] - v;
}

__global__ __launch_bounds__(256) void part_scatter(const int* __restrict__ ei, int E, int EN,
                                                    int NB, int epb,
                                                    const int* __restrict__ base,
                                                    int2* __restrict__ ebuf) {
    __shared__ int cur[512];
    int b = blockIdx.x, t = threadIdx.x;
    for (int i = t; i < NB; i += 256) cur[i] = base[(size_t)i * PBLK + b];
    __syncthreads();
    int e0 = b * epb;
    int e1 = min(e0 + epb, EN);
    for (int e = e0 + t; e < e1; e += 256) {
        int s, d;
        if (e < E) { s = ei[e]; d = ei[E + e]; }
        else       { s = e - E; d = s; }
        int slot = atomicAdd(&cur[d >> 8], 1);
        ebuf[slot] = make_int2(s, d & 255);
    }
}

__global__ __launch_bounds__(256) void bucket_csr(const int2* __restrict__ ebuf,
                                                  const int* __restrict__ bstart,
                                                  int NB, int N, int EN,
                                                  int* __restrict__ row_start,
                                                  int* __restrict__ csr_src) {
    __shared__ int cnt[256];
    __shared__ int sc[256];
    __shared__ int stage[CAP];
    int k = blockIdx.x, t = threadIdx.x;
    int s0 = bstart[k], s1 = bstart[k + 1];
    int len = s1 - s0;
    cnt[t] = 0;
    __syncthreads();
    for (int i = t; i < len; i += 256) atomicAdd(&cnt[ebuf[s0 + i].y], 1);
    __syncthreads();
    int v = cnt[t];
    sc[t] = v;
    __syncthreads();
    for (int off = 1; off < 256; off <<= 1) {
        int u = (t >= off) ? sc[t - off] : 0;
        __syncthreads();
        sc[t] += u;
        __syncthreads();
    }
    int excl = sc[t] - v;
    int g = (k << 8) + t;
    if (g < N) row_start[g] = s0 + excl;
    if (k == NB - 1 && t == 0) row_start[N] = EN;
    bool fits = (len <= CAP);
    cnt[t] = fits ? excl : s0 + excl;
    __syncthreads();
    if (fits) {
        for (int i = t; i < len; i += 256) {
            int2 e = ebuf[s0 + i];
            int slot = atomicAdd(&cnt[e.y], 1);
            stage[slot] = e.x;
        }
        __syncthreads();
        for (int i = t; i < len; i += 256) csr_src[s0 + i] = stage[i];
    } else {
        for (int i = t; i < len; i += 256) {
            int2 e = ebuf[s0 + i];
            int slot = atomicAdd(&cnt[e.y], 1);
            csr_src[slot] = e.x;
        }
    }
}

// ---------------- small converters ----------------

__global__ void xconv_kernel(const float* __restrict__ x, __half* __restrict__ xh, int total4) {
    int t = blockIdx.x * blockDim.x + threadIdx.x;
    if (t >= total4) return;
    float4 v = *reinterpret_cast<const float4*>(x + (size_t)t * 4);
    __half2* op = reinterpret_cast<__half2*>(xh + (size_t)t * 4);
    op[0] = __float22half2_rn(make_float2(v.x, v.y));
    op[1] = __float22half2_rn(make_float2(v.z, v.w));
}

// WT[c][k] = W[k][c], fp16; K = 64 or 128 (kshift = log2 K)
__global__ void wtrans_kernel(const float* __restrict__ W, __half* __restrict__ WT,
                              int K, int kshift) {
    int o = blockIdx.x * blockDim.x + threadIdx.x;
    if (o >= (K << 7)) return;
    int c = o >> kshift;
    int k = o & (K - 1);
    WT[o] = __float2half(W[(size_t)k * 128 + c]);
}

// ------- MFMA GEMM: C[N][128](fp16) = A[N][K](fp16) @ W, + als/ald -------
// Per wave: 16 rows x 128 cols. A frag: [row=lane&15][k=(lane>>4)*8+j] (16B/lane).
// B from WT[col][k]: same shape. C layout: col=lane&15, row=(lane>>4)*4+reg.
// No LDS; WT (<=32KB) broadcast-read from L1/L2.

__global__ __launch_bounds__(256) void gemm_mfma(const __half* __restrict__ A,
                                                 const __half* __restrict__ WT,
                                                 const float* __restrict__ avs,
                                                 const float* __restrict__ avd,
                                                 __half* __restrict__ C,
                                                 float* __restrict__ als,
                                                 float* __restrict__ ald,
                                                 int N, int K) {
    int tid = threadIdx.x;
    int wv = tid >> 6, lane = tid & 63;
    int row0 = blockIdx.x * 64 + wv * 16;
    int lrow = lane & 15;
    int lk = (lane >> 4) * 8;
    int garow = row0 + lrow;

    half8 afrag[4];
#pragma unroll
    for (int ks = 0; ks < 4; ++ks) {
        half8 z = {(_Float16)0, (_Float16)0, (_Float16)0, (_Float16)0,
                   (_Float16)0, (_Float16)0, (_Float16)0, (_Float16)0};
        afrag[ks] = z;
    }
    if (garow < N) {
        const __half* ap = A + (size_t)garow * K + lk;
        if (K == 128) {
#pragma unroll
            for (int ks = 0; ks < 4; ++ks)
                afrag[ks] = *reinterpret_cast<const half8*>(ap + ks * 32);
        } else {
#pragma unroll
            for (int ks = 0; ks < 2; ++ks)
                afrag[ks] = *reinterpret_cast<const half8*>(ap + ks * 32);
        }
    }

    f32x4 acc[8];
#pragma unroll
    for (int t = 0; t < 8; ++t) acc[t] = (f32x4){0.f, 0.f, 0.f, 0.f};

#pragma unroll
    for (int t = 0; t < 8; ++t) {
        const __half* wb = WT + (size_t)(t * 16 + lrow) * K + lk;
        if (K == 128) {
#pragma unroll
            for (int ks = 0; ks < 4; ++ks) {
                half8 bfrag = *reinterpret_cast<const half8*>(wb + ks * 32);
                acc[t] = __builtin_amdgcn_mfma_f32_16x16x32_f16(afrag[ks], bfrag, acc[t], 0, 0, 0);
            }
        } else {
#pragma unroll
            for (int ks = 0; ks < 2; ++ks) {
                half8 bfrag = *reinterpret_cast<const half8*>(wb + ks * 32);
                acc[t] = __builtin_amdgcn_mfma_f32_16x16x32_f16(afrag[ks], bfrag, acc[t], 0, 0, 0);
            }
        }
    }

    int rbase = (lane >> 4) * 4;
    // C store (fp16): per (t,j) lanes 0-15 cover 16 contiguous cols
#pragma unroll
    for (int t = 0; t < 8; ++t) {
#pragma unroll
        for (int j = 0; j < 4; ++j) {
            int gr = row0 + rbase + j;
            if (gr < N) C[(size_t)gr * 128 + t * 16 + lrow] = __float2half(acc[t][j]);
        }
    }
    // als/ald from fp32 acc: per-head partials, reduce over 16 col-lanes
    float ps[4][4], pd[4][4];
#pragma unroll
    for (int h = 0; h < 4; ++h)
#pragma unroll
        for (int j = 0; j < 4; ++j) { ps[h][j] = 0.f; pd[h][j] = 0.f; }
#pragma unroll
    for (int t = 0; t < 8; ++t) {
        int ht = t >> 1;
        float as_c = avs[t * 16 + lrow];
        float ad_c = avd[t * 16 + lrow];
#pragma unroll
        for (int j = 0; j < 4; ++j) {
            ps[ht][j] += acc[t][j] * as_c;
            pd[ht][j] += acc[t][j] * ad_c;
        }
    }
#pragma unroll
    for (int h = 0; h < 4; ++h) {
#pragma unroll
        for (int j = 0; j < 4; ++j) {
            float s = ps[h][j], d = pd[h][j];
            s += __shfl_xor(s, 1); d += __shfl_xor(d, 1);
            s += __shfl_xor(s, 2); d += __shfl_xor(d, 2);
            s += __shfl_xor(s, 4); d += __shfl_xor(d, 4);
            s += __shfl_xor(s, 8); d += __shfl_xor(d, 8);
            if (lrow == 0) {
                int gr = row0 + rbase + j;
                if (gr < N) {
                    als[(size_t)gr * 4 + h] = s;
                    ald[(size_t)gr * 4 + h] = d;
                }
            }
        }
    }
}

// ---------------- wave-per-node aggregation (layers 0-2), fp16 h ----------------

__device__ __forceinline__ float lrelu(float x) { return x > 0.f ? x : NEG_SLOPE * x; }

__global__ __launch_bounds__(256) void agg_kernel(const __half* __restrict__ h,
                                                  const float* __restrict__ als4,
                                                  const float* __restrict__ ald4,
                                                  const int* __restrict__ row_start,
                                                  const int* __restrict__ csr_src,
                                                  const float* __restrict__ bias,
                                                  __half* __restrict__ xout,
                                                  int N, int applyElu) {
    int v = (int)((blockIdx.x * blockDim.x + threadIdx.x) >> 6);
    int lane = threadIdx.x & 63;
    if (v >= N) return;
    int base = row_start[v], end = row_start[v + 1];

    int half_ = lane >> 5;
    int dim4 = (lane & 31) * 4;
    int hd2  = (lane & 31) >> 3;

    float aldh = ald4[(size_t)v * 4 + hd2];
    float alsh = als4[(size_t)v * 4 + hd2];
    float em = lrelu(alsh + aldh);
    const __half* hdim = h + dim4;
    const float* alsb = als4 + hd2;

    float4 acc  = make_float4(0.f, 0.f, 0.f, 0.f);
    float4 acc2 = make_float4(0.f, 0.f, 0.f, 0.f);
    float ssum = 0.f, ssum2 = 0.f;

    int j = base + half_;
    for (; j + 6 < end; j += 8) {
        int s0 = csr_src[j + 0];
        int s1 = csr_src[j + 2];
        int s2 = csr_src[j + 4];
        int s3 = csr_src[j + 6];
        float a0 = alsb[(size_t)s0 * 4];
        float a1 = alsb[(size_t)s1 * 4];
        float a2 = alsb[(size_t)s2 * 4];
        float a3 = alsb[(size_t)s3 * 4];
        uint2 r0 = *reinterpret_cast<const uint2*>(hdim + (size_t)s0 * 128);
        uint2 r1 = *reinterpret_cast<const uint2*>(hdim + (size_t)s1 * 128);
        uint2 r2 = *reinterpret_cast<const uint2*>(hdim + (size_t)s2 * 128);
        uint2 r3 = *reinterpret_cast<const uint2*>(hdim + (size_t)s3 * 128);
        float e0 = __expf(lrelu(a0 + aldh) - em);
        float e1 = __expf(lrelu(a1 + aldh) - em);
        float e2 = __expf(lrelu(a2 + aldh) - em);
        float e3 = __expf(lrelu(a3 + aldh) - em);
        ssum  += e0 + e2;
        ssum2 += e1 + e3;
        float2 f0a = __half22float2(*reinterpret_cast<__half2*>(&r0.x));
        float2 f0b = __half22float2(*reinterpret_cast<__half2*>(&r0.y));
        float2 f1a = __half22float2(*reinterpret_cast<__half2*>(&r1.x));
        float2 f1b = __half22float2(*reinterpret_cast<__half2*>(&r1.y));
        float2 f2a = __half22float2(*reinterpret_cast<__half2*>(&r2.x));
        float2 f2b = __half22float2(*reinterpret_cast<__half2*>(&r2.y));
        float2 f3a = __half22float2(*reinterpret_cast<__half2*>(&r3.x));
        float2 f3b = __half22float2(*reinterpret_cast<__half2*>(&r3.y));
        acc.x  += e0 * f0a.x; acc.y  += e0 * f0a.y; acc.z  += e0 * f0b.x; acc.w  += e0 * f0b.y;
        acc2.x += e1 * f1a.x; acc2.y += e1 * f1a.y; acc2.z += e1 * f1b.x; acc2.w += e1 * f1b.y;
        acc.x  += e2 * f2a.x; acc.y  += e2 * f2a.y; acc.z  += e2 * f2b.x; acc.w  += e2 * f2b.y;
        acc2.x += e3 * f3a.x; acc2.y += e3 * f3a.y; acc2.z += e3 * f3b.x; acc2.w += e3 * f3b.y;
    }
    for (; j < end; j += 2) {
        int s0 = csr_src[j];
        float a0 = alsb[(size_t)s0 * 4];
        uint2 r0 = *reinterpret_cast<const uint2*>(hdim + (size_t)s0 * 128);
        float e0 = __expf(lrelu(a0 + aldh) - em);
        ssum += e0;
        float2 f0a = __half22float2(*reinterpret_cast<__half2*>(&r0.x));
        float2 f0b = __half22float2(*reinterpret_cast<__half2*>(&r0.y));
        acc.x += e0 * f0a.x; acc.y += e0 * f0a.y; acc.z += e0 * f0b.x; acc.w += e0 * f0b.y;
    }
    acc.x += acc2.x; acc.y += acc2.y; acc.z += acc2.z; acc.w += acc2.w;
    ssum += ssum2;
    acc.x += __shfl_xor(acc.x, 32);
    acc.y += __shfl_xor(acc.y, 32);
    acc.z += __shfl_xor(acc.z, 32);
    acc.w += __shfl_xor(acc.w, 32);
    ssum  += __shfl_xor(ssum, 32);

    if (lane < 32) {
        float inv = 1.0f / (ssum + 1e-16f);
        float4 bv = *reinterpret_cast<const float4*>(bias + dim4);
        float4 o;
        o.x = acc.x * inv + bv.x;
        o.y = acc.y * inv + bv.y;
        o.z = acc.z * inv + bv.z;
        o.w = acc.w * inv + bv.w;
        if (applyElu) {
            o.x = o.x > 0.f ? o.x : expm1f(o.x);
            o.y = o.y > 0.f ? o.y : expm1f(o.y);
            o.z = o.z > 0.f ? o.z : expm1f(o.z);
            o.w = o.w > 0.f ? o.w : expm1f(o.w);
        }
        __half2* op = reinterpret_cast<__half2*>(xout + (size_t)v * 128 + dim4);
        op[0] = __float22half2_rn(make_float2(o.x, o.y));
        op[1] = __float22half2_rn(make_float2(o.z, o.w));
    }
}

// ---------------- layer 3: GEMM [N,128]x[128,6] with fused al ----------------

__global__ void gemm3_kernel(const __half* __restrict__ x, const float* __restrict__ W,
                             const float* __restrict__ as3, const float* __restrict__ ad3,
                             float* __restrict__ h3, float* __restrict__ als3,
                             float* __restrict__ ald3, int N) {
    int n = blockIdx.x * blockDim.x + threadIdx.x;
    if (n >= N) return;
    float acc[6] = {0.f, 0.f, 0.f, 0.f, 0.f, 0.f};
    const __half* xp = x + (size_t)n * 128;
#pragma unroll 2
    for (int k8 = 0; k8 < 16; ++k8) {
        uint4 rv = *reinterpret_cast<const uint4*>(xp + k8 * 8);
        float2 fa = __half22float2(*reinterpret_cast<__half2*>(&rv.x));
        float2 fb = __half22float2(*reinterpret_cast<__half2*>(&rv.y));
        float2 fc = __half22float2(*reinterpret_cast<__half2*>(&rv.z));
        float2 fd = __half22float2(*reinterpret_cast<__half2*>(&rv.w));
        float xv[8] = {fa.x, fa.y, fb.x, fb.y, fc.x, fc.y, fd.x, fd.y};
        const float* w0 = W + (size_t)(k8 * 8) * 6;
#pragma unroll
        for (int kk = 0; kk < 8; ++kk)
#pragma unroll
            for (int q = 0; q < 6; ++q)
                acc[q] += xv[kk] * w0[kk * 6 + q];
    }
    float s = 0.f, d = 0.f;
#pragma unroll
    for (int q = 0; q < 6; ++q) {
        s += acc[q] * as3[q];
        d += acc[q] * ad3[q];
        h3[(size_t)n * 6 + q] = acc[q];
    }
    als3[n] = s;
    ald3[n] = d;
}

__global__ void agg3_kernel(const float* __restrict__ h3, const float* __restrict__ als3,
                            const float* __restrict__ ald3, const int* __restrict__ row_start,
                            const int* __restrict__ csr_src, const float* __restrict__ b3,
                            float* __restrict__ out, int N) {
    int v = blockIdx.x * blockDim.x + threadIdx.x;
    if (v >= N) return;
    int base = row_start[v], end = row_start[v + 1];
    float aldv = ald3[v];
    float em = lrelu(als3[v] + aldv);
    float ssum = 0.f;
    float acc[6] = {0.f, 0.f, 0.f, 0.f, 0.f, 0.f};
    float acc2[6] = {0.f, 0.f, 0.f, 0.f, 0.f, 0.f};
    int j = base;
    for (; j + 1 < end; j += 2) {
        int sa = csr_src[j], sb = csr_src[j + 1];
        float ea = __expf(lrelu(als3[sa] + aldv) - em);
        float eb = __expf(lrelu(als3[sb] + aldv) - em);
        ssum += ea + eb;
        const float* ha = h3 + (size_t)sa * 6;
        const float* hb = h3 + (size_t)sb * 6;
#pragma unroll
        for (int q = 0; q < 6; ++q) acc[q] += ea * ha[q];
#pragma unroll
        for (int q = 0; q < 6; ++q) acc2[q] += eb * hb[q];
    }
    if (j < end) {
        int sa = csr_src[j];
        float ea = __expf(lrelu(als3[sa] + aldv) - em);
        ssum += ea;
        const float* ha = h3 + (size_t)sa * 6;
#pragma unroll
        for (int q = 0; q < 6; ++q) acc[q] += ea * ha[q];
    }
    float inv = 1.f / (ssum + 1e-16f);
#pragma unroll
    for (int q = 0; q < 6; ++q) out[(size_t)v * 6 + q] = (acc[q] + acc2[q]) * inv + b3[q];
}

// ---------------- launch ----------------

extern "C" void kernel_launch(void* const* d_in, const int* in_sizes, int n_in,
                              void* d_out, int out_size, void* d_ws, size_t ws_size,
                              hipStream_t stream) {
    const float* x    = (const float*)d_in[0];
    const int*   ei   = (const int*)d_in[1];
    const float* W0   = (const float*)d_in[3];
    const float* as0  = (const float*)d_in[4];
    const float* ad0  = (const float*)d_in[5];
    const float* b0   = (const float*)d_in[6];
    const float* W1   = (const float*)d_in[7];
    const float* as1  = (const float*)d_in[8];
    const float* ad1  = (const float*)d_in[9];
    const float* b1   = (const float*)d_in[10];
    const float* W2   = (const float*)d_in[11];
    const float* as2  = (const float*)d_in[12];
    const float* ad2  = (const float*)d_in[13];
    const float* b2   = (const float*)d_in[14];
    const float* W3   = (const float*)d_in[15];
    const float* as3  = (const float*)d_in[16];
    const float* ad3  = (const float*)d_in[17];
    const float* b3   = (const float*)d_in[18];
    float* out = (float*)d_out;

    int N = in_sizes[0] / IN_CH;
    int E = in_sizes[1] / 2;
    int EN = E + N;
    int NB = (N + 255) >> 8;
    int epb = (EN + PBLK - 1) / PBLK;

    char* p = (char*)d_ws;
    auto alloc = [&](size_t bytes) {
        char* q = p;
        p += (bytes + 255) & ~(size_t)255;
        return q;
    };
    __half* xh   = (__half*)alloc((size_t)N * 64 * 2);
    __half* hbuf = (__half*)alloc((size_t)N * 128 * 2);
    __half* xA   = (__half*)alloc((size_t)N * 128 * 2);
    __half* xB   = (__half*)alloc((size_t)N * 128 * 2);
    __half* WT0  = (__half*)alloc((size_t)128 * 64 * 2);
    __half* WT1  = (__half*)alloc((size_t)128 * 128 * 2);
    __half* WT2  = (__half*)alloc((size_t)128 * 128 * 2);
    float* als  = (float*)alloc((size_t)N * 4 * 4);
    float* ald  = (float*)alloc((size_t)N * 4 * 4);
    float* h3   = (float*)alloc((size_t)N * 6 * 4);
    float* als3 = (float*)alloc((size_t)N * 4);
    float* ald3 = (float*)alloc((size_t)N * 4);
    int* row_start = (int*)alloc((size_t)(N + 1) * 4);
    int* csr_src   = (int*)alloc((size_t)EN * 4);
    int2* ebuf     = (int2*)alloc((size_t)EN * 8);
    int* counts    = (int*)alloc((size_t)NB * PBLK * 4);
    int* btot      = (int*)alloc((size_t)NB * 4);
    int* bstart    = (int*)alloc((size_t)(NB + 1) * 4);
    (void)ws_size; (void)n_in; (void)out_size;

    // ---- CSR build (no global atomics) ----
    part_count<<<PBLK, 256, 0, stream>>>(ei, E, EN, NB, epb, counts);
    bucket_tot<<<NB, 256, 0, stream>>>(counts, btot);
    bucket_scan<<<1, 256, 0, stream>>>(btot, NB, EN, bstart);
    bucket_base<<<NB, 256, 0, stream>>>(counts, bstart);
    part_scatter<<<PBLK, 256, 0, stream>>>(ei, E, EN, NB, epb, counts, ebuf);
    bucket_csr<<<NB, 256, 0, stream>>>(ebuf, bstart, NB, N, EN, row_start, csr_src);

    // ---- weight / input conversion ----
    xconv_kernel<<<(N * 16 + 255) / 256, 256, 0, stream>>>(x, xh, N * 16);
    wtrans_kernel<<<(128 * 64 + 255) / 256, 256, 0, stream>>>(W0, WT0, 64, 6);
    wtrans_kernel<<<(128 * 128 + 255) / 256, 256, 0, stream>>>(W1, WT1, 128, 7);
    wtrans_kernel<<<(128 * 128 + 255) / 256, 256, 0, stream>>>(W2, WT2, 128, 7);

    int gemm_grid = (N + 63) / 64;
    int agg_grid  = (N + 3) / 4;
    int n_grid    = (N + 255) / 256;

    // ---- layer 0 ----
    gemm_mfma<<<gemm_grid, 256, 0, stream>>>(xh, WT0, as0, ad0, hbuf, als, ald, N, 64);
    agg_kernel<<<agg_grid, 256, 0, stream>>>(hbuf, als, ald, row_start, csr_src, b0, xA, N, 1);

    // ---- layer 1 ----
    gemm_mfma<<<gemm_grid, 256, 0, stream>>>(xA, WT1, as1, ad1, hbuf, als, ald, N, 128);
    agg_kernel<<<agg_grid, 256, 0, stream>>>(hbuf, als, ald, row_start, csr_src, b1, xB, N, 1);

    // ---- layer 2 ----
    gemm_mfma<<<gemm_grid, 256, 0, stream>>>(xB, WT2, as2, ad2, hbuf, als, ald, N, 128);
    agg_kernel<<<agg_grid, 256, 0, stream>>>(hbuf, als, ald, row_start, csr_src, b2, xA, N, 1);

    // ---- layer 3 ----
    gemm3_kernel<<<n_grid, 256, 0, stream>>>(xA, W3, as3, ad3, h3, als3, ald3, N);
    agg3_kernel<<<n_grid, 256, 0, stream>>>(h3, als3, ald3, row_start, csr_src, b3, out, N);
}